// Round 16
// baseline (2767.665 us; speedup 1.0000x reference)
//
#include <hip/hip_runtime.h>

// Problem constants
#define BB 4
#define SS 32
#define CC 128
#define HH 16
#define WW 32
#define HID 128
#define DEPTH 2
#define CIN 256           // CC + HID
#define COUT 512          // 4*HID
#define K9 (CIN * 9)      // 2304
#define KH 1152           // per-source K: tap-major k = tap*128 + ch
#define KFULL (2 * KH)    // 2304 = x-part rows then h-part rows
#define HW (HH * WW)      // 512
#define MM (BB * HW)      // 2048
#define ACT (BB * HW * 128) // 262144 = one activation slice (b,hw,ch)

typedef __attribute__((ext_vector_type(4))) float f32x4;
typedef __attribute__((ext_vector_type(8))) short bf16x8;

static __device__ __forceinline__ unsigned short f2bf(float f) {
    union { float f; unsigned u; } v; v.f = f;
    unsigned r = v.u + 0x7FFF + ((v.u >> 16) & 1);   // RNE
    return (unsigned short)(r >> 16);
}
static __device__ __forceinline__ float bf2f(unsigned short h) {
    union { float f; unsigned u; } v; v.u = ((unsigned)h) << 16; return v.f;
}
static __device__ __forceinline__ bf16x8 u4bf(uint4 v) {
    union { uint4 u; bf16x8 b; } c; c.u = v; return c.b;
}

// ---------------------------------------------------------------------------
// Weight transpose -> separate hi/lo bf16 planes, k-major:
//   wh/wl [DEPTH][COUT_g][KFULL] ushort
// k row: cin<CC -> tap*CC+cin (x block) else KH + tap*HID + (cin-CC) (h block)
// n gate-gathered: n' = (r>>4)*64 + g*16 + (r&15)
// ---------------------------------------------------------------------------
__global__ void transpose_w_kernel(const float* __restrict__ w,
                                   unsigned short* __restrict__ wh,
                                   unsigned short* __restrict__ wl) {
    int idx = blockIdx.x * 256 + threadIdx.x;
    if (idx >= DEPTH * K9 * COUT) return;
    int n = idx % COUT;
    int k = (idx / COUT) % K9;
    int d = idx / (COUT * K9);
    int cin = k / 9, tap = k % 9;
    float v = w[(((long)(d * COUT + n) * CIN + cin) * 9) + tap];
    int row = (cin < CC) ? (tap * CC + cin) : (KH + tap * HID + (cin - CC));
    int g = n >> 7, r = n & 127;
    int ng = (r >> 4) * 64 + g * 16 + (r & 15);
    unsigned short hi = f2bf(v);
    unsigned short lo = f2bf(v - bf2f(hi));
    long o = ((long)d * COUT + ng) * KFULL + row;
    wh[o] = hi;
    wl[o] = lo;
}

// ---------------------------------------------------------------------------
// Pack x [B][S][CC][HW] fp32 -> hi/lo planes [s][b][hw][cc] via LDS transpose.
// grid (SS*BB, HW/64), 256 threads.
// ---------------------------------------------------------------------------
__global__ void pack_x_kernel(const float* __restrict__ x,
                              unsigned* __restrict__ xh32,
                              unsigned* __restrict__ xl32) {
    __shared__ unsigned lh[128 * 33], ll[128 * 33];   // [cc][hw-pair], pad 33
    const int tid = threadIdx.x;
    const int sb  = blockIdx.x;          // s*BB + b
    const int s   = sb >> 2;
    const int b   = sb & 3;
    const int hw0 = blockIdx.y * 64;
    const float* src = x + ((long)(b * SS + s) * CC) * HW;

    #pragma unroll
    for (int it = 0; it < 16; ++it) {
        int cc = it * 8 + (tid >> 5);
        int hw = (tid & 31) * 2;
        float2 v = *(const float2*)&src[cc * HW + hw0 + hw];
        unsigned short h0 = f2bf(v.x), h1 = f2bf(v.y);
        unsigned short l0 = f2bf(v.x - bf2f(h0)), l1 = f2bf(v.y - bf2f(h1));
        lh[cc * 33 + (hw >> 1)] = (unsigned)h0 | ((unsigned)h1 << 16);
        ll[cc * 33 + (hw >> 1)] = (unsigned)l0 | ((unsigned)l1 << 16);
    }
    __syncthreads();
    const unsigned short* lhs = (const unsigned short*)lh;
    const unsigned short* lls = (const unsigned short*)ll;
    #pragma unroll
    for (int it = 0; it < 16; ++it) {
        int hw = it * 4 + (tid >> 6);
        int c2 = tid & 63;               // cc pair
        unsigned short a0 = lhs[(2 * c2) * 66 + hw];
        unsigned short a1 = lhs[(2 * c2 + 1) * 66 + hw];
        unsigned short b0 = lls[(2 * c2) * 66 + hw];
        unsigned short b1 = lls[(2 * c2 + 1) * 66 + hw];
        long o = ((long)sb * HW + hw0 + hw) * 64 + c2;
        xh32[o] = (unsigned)a0 | ((unsigned)a1 << 16);
        xl32[o] = (unsigned)b0 | ((unsigned)b1 << 16);
    }
}

// ---------------------------------------------------------------------------
// Broadcast init_h/init_c[d] into hi/lo h planes ([b][hw][hid]) + fp32 c
// ---------------------------------------------------------------------------
__global__ void init_state_kernel(const float* __restrict__ ih, const float* __restrict__ ic,
                                  unsigned short* __restrict__ hh, unsigned short* __restrict__ hl,
                                  float* __restrict__ c, int d) {
    int idx = blockIdx.x * 256 + threadIdx.x;   // ACT = 262144
    int hid = idx & 127;
    float v = ih[d * HID + hid];
    unsigned short hi = f2bf(v);
    hh[idx] = hi;
    hl[idx] = f2bf(v - bf2f(hi));
    c[idx] = ic[d * HID + hid];
}

// Zero the 256B OOB page (workspace is poisoned 0xAA before timing)
__global__ void zero_kernel(unsigned* __restrict__ zp) { zp[threadIdx.x] = 0u; }

// ---------------------------------------------------------------------------
// DUAL-LAYER fused step kernel.
//  - A (activations) staged in LDS, XOR-swizzled, conflict-free reads AND
//    writes (wave stages 16 contiguous rows -> 1024B-contiguous ds_writes).
//  - B (weights) read DIRECTLY global->registers (k-major: lane frag = one
//    uint4; L2/L1-resident panel per XCD). LDS traffic halves; L2 path runs
//    in parallel with LDS unit. Register ping-pong via manual unroll-2.
// M=64, N=64 per wg, 256 thr = 4 waves (2m x 2n of 32x32 from 16x16 frags).
// BK=64, single barrier per tile. Grid 512 flat, XCD-stable swizzle.
// K = 36 tiles: tt<18 from x-source, tt>=18 from h-source (tap-major).
// ---------------------------------------------------------------------------
__launch_bounds__(256)
__global__ void step_dual(
    const unsigned short* __restrict__ x1h, const unsigned short* __restrict__ x1l,
    const unsigned short* __restrict__ h1h, const unsigned short* __restrict__ h1l,
    float* __restrict__ c1, unsigned short* __restrict__ o1h, unsigned short* __restrict__ o1l,
    const unsigned short* __restrict__ x2h, const unsigned short* __restrict__ x2l,
    const unsigned short* __restrict__ h2h, const unsigned short* __restrict__ h2l,
    float* __restrict__ c2, unsigned short* __restrict__ o2h, unsigned short* __restrict__ o2l,
    const unsigned short* __restrict__ wh, const unsigned short* __restrict__ wl,
    const float* __restrict__ bias, const unsigned short* __restrict__ zp,
    int do1, int do2)
{
    // A-only LDS: hi [0,4096), lo [4096,8192) per buffer; 2 buffers = 32 KB.
    __shared__ __align__(16) unsigned short lds[2][8192];

    const int bid  = blockIdx.x;
    const int xcd  = bid & 7;
    const int q    = bid >> 3;               // 0..63
    const int mblk = q & 31;
    const int pp   = xcd + ((q >> 5) << 3);  // panel 0..15
    const int nblk = pp & 7;
    const int z    = pp >> 3;
    if (z == 0) { if (!do1) return; } else { if (!do2) return; }

    const unsigned short* axh = z ? x2h : x1h;
    const unsigned short* axl = z ? x2l : x1l;
    const unsigned short* ahh = z ? h2h : h1h;
    const unsigned short* ahl = z ? h2l : h1l;
    const unsigned short* wph = wh + (long)z * COUT * KFULL;
    const unsigned short* wpl = wl + (long)z * COUT * KFULL;
    const float* bsel  = bias + z * COUT;
    float* csel        = z ? c2 : c1;
    unsigned short* ohh = z ? o2h : o1h;
    unsigned short* ohl = z ? o2l : o1l;

    const int m0   = mblk * 64;
    const int n0g  = nblk * 64;
    const int hid0 = nblk * 16;
    const int tid  = threadIdx.x;
    const int lane = tid & 63;
    const int wv   = tid >> 6;              // wave 0..3
    const int wm   = (wv >> 1) * 32;        // wave m offset (32x32 tile)
    const int wn   = (wv & 1) * 32;         // wave n offset
    const int b    = m0 >> 9;
    const int hwl  = m0 & 511;
    const int y0   = hwl >> 5;              // first image row (2 rows per wg)

    // --- A staging geometry: wave wv stages rows 16wv..16wv+15 ---
    // lane: row1 = 16wv + (lane>>3), row2 = row1+8, chunk j = lane&7
    // LDS slot j holds source chunk j^(row&7); writes are 1024B-contiguous.
    const int row1 = wv * 16 + (lane >> 3);
    const int row2 = row1 + 8;
    const int jch  = lane & 7;
    const int jx1  = jch ^ (row1 & 7);
    const int jx2  = jch ^ (row2 & 7);
    const int sx1  = row1 & 31, sy1b = row1 >> 5;
    const int sx2  = row2 & 31, sy2b = row2 >> 5;
    const long bhw = (long)b * HW;
    const int seg1 = row1 * 64 + jch * 8;
    const int seg2 = row2 * 64 + jch * 8;

    uint4 rah1v, rah2v, ral1v, ral2v;
    auto ldA = [&](int tt) {
        int ksub = (tt < 18) ? tt : tt - 18;
        int tap  = ksub >> 1;
        int c0   = (ksub & 1) << 6;
        int ky   = tap / 3 - 1;
        int kx   = tap - (tap / 3) * 3 - 1;
        const unsigned short* sh = (tt < 18) ? axh : ahh;
        const unsigned short* sl = (tt < 18) ? axl : ahl;
        int yy1 = y0 + sy1b + ky, xq1 = sx1 + kx;
        int yy2 = y0 + sy2b + ky, xq2 = sx2 + kx;
        bool ok1 = (unsigned)yy1 < (unsigned)HH && (unsigned)xq1 < (unsigned)WW;
        bool ok2 = (unsigned)yy2 < (unsigned)HH && (unsigned)xq2 < (unsigned)WW;
        long a1 = ((bhw + yy1 * WW + xq1) << 7) + c0 + jx1 * 8;
        long a2 = ((bhw + yy2 * WW + xq2) << 7) + c0 + jx2 * 8;
        rah1v = *(const uint4*)(ok1 ? sh + a1 : zp);
        ral1v = *(const uint4*)(ok1 ? sl + a1 : zp);
        rah2v = *(const uint4*)(ok2 ? sh + a2 : zp);
        ral2v = *(const uint4*)(ok2 ? sl + a2 : zp);
    };
    auto commitA = [&](int pb) {
        *(uint4*)&lds[pb][seg1]        = rah1v;
        *(uint4*)&lds[pb][seg2]        = rah2v;
        *(uint4*)&lds[pb][4096 + seg1] = ral1v;
        *(uint4*)&lds[pb][4096 + seg2] = ral2v;
    };

    // --- B direct-from-global fragment addresses ---
    const int fr  = lane & 15;
    const int kqi = lane >> 4;              // 0..3
    const long brow0 = (long)(n0g + wn + fr) * KFULL + kqi * 8;
    const long brow1 = brow0 + 16L * KFULL;

    f32x4 acc00 = (f32x4){0.f,0.f,0.f,0.f};
    f32x4 acc01 = (f32x4){0.f,0.f,0.f,0.f};
    f32x4 acc10 = (f32x4){0.f,0.f,0.f,0.f};
    f32x4 acc11 = (f32x4){0.f,0.f,0.f,0.f};

    const int am0 = wm + fr;                // A rows (2 m-frags)
    const int am1 = wm + 16 + fr;

    // B register sets (ping-pong): [sub][{h0,h1,l0,l1}]
    uint4 A0h0, A0h1, A0l0, A0l1, A1h0, A1h1, A1l0, A1l1;   // set A
    uint4 B0h0, B0h1, B0l0, B0l1, B1h0, B1h1, B1l0, B1l1;   // set B

#define LDB(K0, S0h0,S0h1,S0l0,S0l1,S1h0,S1h1,S1l0,S1l1) do {          \
        long kk = (long)(K0);                                          \
        S0h0 = *(const uint4*)(wph + brow0 + kk);                      \
        S0h1 = *(const uint4*)(wph + brow1 + kk);                      \
        S0l0 = *(const uint4*)(wpl + brow0 + kk);                      \
        S0l1 = *(const uint4*)(wpl + brow1 + kk);                      \
        S1h0 = *(const uint4*)(wph + brow0 + kk + 32);                 \
        S1h1 = *(const uint4*)(wph + brow1 + kk + 32);                 \
        S1l0 = *(const uint4*)(wpl + brow0 + kk + 32);                 \
        S1l1 = *(const uint4*)(wpl + brow1 + kk + 32);                 \
    } while (0)

#define COMPUTE(P, S0h0,S0h1,S0l0,S0l1,S1h0,S1h1,S1l0,S1l1) do {                         \
        const unsigned short* L = &lds[P][0];                                            \
        __builtin_amdgcn_s_setprio(1);                                                   \
        {   const int ca = kqi;                                                          \
            bf16x8 ah0 = *(const bf16x8*)&L[am0 * 64 + ((ca ^ (am0 & 7)) << 3)];         \
            bf16x8 ah1 = *(const bf16x8*)&L[am1 * 64 + ((ca ^ (am1 & 7)) << 3)];         \
            bf16x8 al0 = *(const bf16x8*)&L[4096 + am0 * 64 + ((ca ^ (am0 & 7)) << 3)];  \
            bf16x8 al1 = *(const bf16x8*)&L[4096 + am1 * 64 + ((ca ^ (am1 & 7)) << 3)];  \
            bf16x8 bh0 = u4bf(S0h0), bh1 = u4bf(S0h1);                                   \
            bf16x8 bl0 = u4bf(S0l0), bl1 = u4bf(S0l1);                                   \
            acc00 = __builtin_amdgcn_mfma_f32_16x16x32_bf16(ah0, bh0, acc00, 0, 0, 0);   \
            acc01 = __builtin_amdgcn_mfma_f32_16x16x32_bf16(ah0, bh1, acc01, 0, 0, 0);   \
            acc10 = __builtin_amdgcn_mfma_f32_16x16x32_bf16(ah1, bh0, acc10, 0, 0, 0);   \
            acc11 = __builtin_amdgcn_mfma_f32_16x16x32_bf16(ah1, bh1, acc11, 0, 0, 0);   \
            acc00 = __builtin_amdgcn_mfma_f32_16x16x32_bf16(ah0, bl0, acc00, 0, 0, 0);   \
            acc01 = __builtin_amdgcn_mfma_f32_16x16x32_bf16(ah0, bl1, acc01, 0, 0, 0);   \
            acc10 = __builtin_amdgcn_mfma_f32_16x16x32_bf16(ah1, bl0, acc10, 0, 0, 0);   \
            acc11 = __builtin_amdgcn_mfma_f32_16x16x32_bf16(ah1, bl1, acc11, 0, 0, 0);   \
            acc00 = __builtin_amdgcn_mfma_f32_16x16x32_bf16(al0, bh0, acc00, 0, 0, 0);   \
            acc01 = __builtin_amdgcn_mfma_f32_16x16x32_bf16(al0, bh1, acc01, 0, 0, 0);   \
            acc10 = __builtin_amdgcn_mfma_f32_16x16x32_bf16(al1, bh0, acc10, 0, 0, 0);   \
            acc11 = __builtin_amdgcn_mfma_f32_16x16x32_bf16(al1, bh1, acc11, 0, 0, 0);   \
        }                                                                                \
        {   const int ca = 4 + kqi;                                                      \
            bf16x8 ah0 = *(const bf16x8*)&L[am0 * 64 + ((ca ^ (am0 & 7)) << 3)];         \
            bf16x8 ah1 = *(const bf16x8*)&L[am1 * 64 + ((ca ^ (am1 & 7)) << 3)];         \
            bf16x8 al0 = *(const bf16x8*)&L[4096 + am0 * 64 + ((ca ^ (am0 & 7)) << 3)];  \
            bf16x8 al1 = *(const bf16x8*)&L[4096 + am1 * 64 + ((ca ^ (am1 & 7)) << 3)];  \
            bf16x8 bh0 = u4bf(S1h0), bh1 = u4bf(S1h1);                                   \
            bf16x8 bl0 = u4bf(S1l0), bl1 = u4bf(S1l1);                                   \
            acc00 = __builtin_amdgcn_mfma_f32_16x16x32_bf16(ah0, bh0, acc00, 0, 0, 0);   \
            acc01 = __builtin_amdgcn_mfma_f32_16x16x32_bf16(ah0, bh1, acc01, 0, 0, 0);   \
            acc10 = __builtin_amdgcn_mfma_f32_16x16x32_bf16(ah1, bh0, acc10, 0, 0, 0);   \
            acc11 = __builtin_amdgcn_mfma_f32_16x16x32_bf16(ah1, bh1, acc11, 0, 0, 0);   \
            acc00 = __builtin_amdgcn_mfma_f32_16x16x32_bf16(ah0, bl0, acc00, 0, 0, 0);   \
            acc01 = __builtin_amdgcn_mfma_f32_16x16x32_bf16(ah0, bl1, acc01, 0, 0, 0);   \
            acc10 = __builtin_amdgcn_mfma_f32_16x16x32_bf16(ah1, bl1, acc10, 0, 0, 0);   \
            acc11 = __builtin_amdgcn_mfma_f32_16x16x32_bf16(ah1, bl1, acc11, 0, 0, 0);   \
            acc10 = __builtin_amdgcn_mfma_f32_16x16x32_bf16(al1, bh0, acc10, 0, 0, 0);   \
            acc11 = __builtin_amdgcn_mfma_f32_16x16x32_bf16(al1, bh1, acc11, 0, 0, 0);   \
            acc00 = __builtin_amdgcn_mfma_f32_16x16x32_bf16(al0, bh0, acc00, 0, 0, 0);   \
            acc01 = __builtin_amdgcn_mfma_f32_16x16x32_bf16(al0, bh1, acc01, 0, 0, 0);   \
        }                                                                                \
        __builtin_amdgcn_s_setprio(0);                                                   \
    } while (0)

    // NOTE on sub-1 block ordering: the MFMA set is identical (same 12
    // products accumulated into the same accumulators); order within the
    // unrolled block does not change the per-accumulator summation order.

    LDB(0, A0h0,A0h1,A0l0,A0l1,A1h0,A1h1,A1l0,A1l1);
    ldA(0); commitA(0);
    __syncthreads();

    int p = 0;
    for (int tt = 0; tt < 36; tt += 2) {
        // even tile: compute with set A, prefetch tt+1 into set B
        ldA(tt + 1);
        LDB((long)(tt + 1) * 64, B0h0,B0h1,B0l0,B0l1,B1h0,B1h1,B1l0,B1l1);
        COMPUTE(p, A0h0,A0h1,A0l0,A0l1,A1h0,A1h1,A1l0,A1l1);
        commitA(1 - p);
        __syncthreads();
        p ^= 1;
        // odd tile: compute with set B, prefetch tt+2 into set A
        if (tt + 2 < 36) {
            ldA(tt + 2);
            LDB((long)(tt + 2) * 64, A0h0,A0h1,A0l0,A0l1,A1h0,A1h1,A1l0,A1l1);
        }
        COMPUTE(p, B0h0,B0h1,B0l0,B0l1,B1h0,B1h1,B1l0,B1l1);
        if (tt + 2 < 36) {
            commitA(1 - p);
            __syncthreads();
            p ^= 1;
        }
    }
    __syncthreads();

#undef LDB
#undef COMPUTE

    // --- epilogue: z-tile via LDS (reuse both buffers), LSTM cell update ---
    float* zt = (float*)&lds[0][0];         // [64 n_gathered][68 m] = 17.4 KB
    {
        const int rm = (lane >> 4) * 4;
        const int cn = lane & 15;
        *(float4*)&zt[(wn + cn) * 68 + wm + rm]           = *(float4*)&acc00;
        *(float4*)&zt[(wn + 16 + cn) * 68 + wm + rm]      = *(float4*)&acc01;
        *(float4*)&zt[(wn + cn) * 68 + wm + 16 + rm]      = *(float4*)&acc10;
        *(float4*)&zt[(wn + 16 + cn) * 68 + wm + 16 + rm] = *(float4*)&acc11;
    }
    __syncthreads();

    #pragma unroll
    for (int i2 = 0; i2 < 4; ++i2) {        // 1024 cell elems, 4/thread
        int e  = i2 * 256 + tid;
        int m  = e & 63;
        int jh = e >> 6;                    // hid slice 0..15
        float g4[4];
        #pragma unroll
        for (int gi = 0; gi < 4; ++gi)
            g4[gi] = zt[(gi * 16 + jh) * 68 + m] + bsel[gi * 128 + hid0 + jh];
        long idx = ((long)b * HW + hwl + m) * 128 + hid0 + jh;
        float si = 1.f / (1.f + expf(-g4[0]));
        float sf = 1.f / (1.f + expf(-g4[1]));
        float so = 1.f / (1.f + expf(-g4[3]));
        float cs = sf * csel[idx] + si * tanhf(g4[2]);
        float hs = so * tanhf(cs);
        csel[idx] = cs;
        unsigned short hi = f2bf(hs);
        ohh[idx] = hi;
        ohl[idx] = f2bf(hs - bf2f(hi));
    }
}

// ---------------------------------------------------------------------------
// Mean pool over HW: seq2 planes [s][b][hw][hid] -> pooled [(s*BB+b)*HID + j]
// ---------------------------------------------------------------------------
__global__ void pool_kernel(const unsigned short* __restrict__ s2h,
                            const unsigned short* __restrict__ s2l,
                            float* __restrict__ pooled) {
    int bs = blockIdx.x;            // s*BB + b
    int j  = threadIdx.x;           // 0..127
    const unsigned short* ph = s2h + (long)bs * HW * 128 + j;
    const unsigned short* pl = s2l + (long)bs * HW * 128 + j;
    float sum = 0.f;
    #pragma unroll 8
    for (int hw = 0; hw < HW; ++hw)
        sum += bf2f(ph[hw * 128]) + bf2f(pl[hw * 128]);
    pooled[bs * HID + j] = sum * (1.f / HW);
}

// ---------------------------------------------------------------------------
// FC + ReLU + two scalar heads.
// ---------------------------------------------------------------------------
__global__ void head_kernel(const float* __restrict__ pooled,
                            const float* __restrict__ fc_w, const float* __restrict__ fc_b,
                            const float* __restrict__ fco_w, const float* __restrict__ fco_b,
                            const float* __restrict__ fca_w, const float* __restrict__ fca_b,
                            float* __restrict__ out) {
    int bs = blockIdx.x;          // b*S + s
    int b  = bs / SS;
    int s  = bs % SS;
    int j  = threadIdx.x;
    const float* prow = pooled + (long)(s * BB + b) * HID;
    float acc = fc_b[j];
    #pragma unroll 4
    for (int k = 0; k < HID; ++k) acc += fc_w[j * HID + k] * prow[k];
    float f = fmaxf(acc, 0.f);
    __shared__ float ro[128], ra[128];
    ro[j] = f * fco_w[j];
    ra[j] = f * fca_w[j];
    __syncthreads();
    for (int off = 64; off; off >>= 1) {
        if (j < off) { ro[j] += ro[j + off]; ra[j] += ra[j + off]; }
        __syncthreads();
    }
    if (j == 0) {
        out[bs]           = ro[0] + fco_b[0];
        out[BB * SS + bs] = ra[0] + fca_b[0];
    }
}

// ---------------------------------------------------------------------------
extern "C" void kernel_launch(void* const* d_in, const int* in_sizes, int n_in,
                              void* d_out, int out_size, void* d_ws, size_t ws_size,
                              hipStream_t stream) {
    const float* x      = (const float*)d_in[0];
    const float* conv_w = (const float*)d_in[1];
    const float* conv_b = (const float*)d_in[2];
    const float* init_h = (const float*)d_in[3];
    const float* init_c = (const float*)d_in[4];
    const float* fc_w   = (const float*)d_in[5];
    const float* fc_b   = (const float*)d_in[6];
    const float* fco_w  = (const float*)d_in[7];
    const float* fco_b  = (const float*)d_in[8];
    const float* fca_w  = (const float*)d_in[9];
    const float* fca_b  = (const float*)d_in[10];
    float* out = (float*)d_out;

    // Workspace carve-up (ushort planes first, then fp32) — total ~114 MB.
    unsigned short* wh  = (unsigned short*)d_ws;            // 2,359,296
    unsigned short* wl  = wh  + (long)DEPTH * COUT * KFULL; // 2,359,296
    unsigned short* xph = wl  + (long)DEPTH * COUT * KFULL; // SS*ACT = 8,388,608
    unsigned short* xpl = xph + (long)SS * ACT;
    unsigned short* s1h = xpl + (long)SS * ACT;
    unsigned short* s1l = s1h + (long)SS * ACT;
    unsigned short* s2h = s1l + (long)SS * ACT;
    unsigned short* s2l = s2h + (long)SS * ACT;
    unsigned short* h1h = s2l + (long)SS * ACT;             // ACT each
    unsigned short* h1l = h1h + ACT;
    unsigned short* h2h = h1l + ACT;
    unsigned short* h2l = h2h + ACT;
    float* c1     = (float*)(h2l + ACT);                    // ACT f32
    float* c2     = c1 + ACT;
    float* pooled = c2 + ACT;                               // 16,384
    unsigned short* zp = (unsigned short*)(pooled + SS * BB * HID); // 256 B zeros

    transpose_w_kernel<<<(DEPTH * K9 * COUT + 255) / 256, 256, 0, stream>>>(conv_w, wh, wl);
    pack_x_kernel<<<dim3(SS * BB, HW / 64), 256, 0, stream>>>(x, (unsigned*)xph, (unsigned*)xpl);
    init_state_kernel<<<ACT / 256, 256, 0, stream>>>(init_h, init_c, h1h, h1l, c1, 0);
    init_state_kernel<<<ACT / 256, 256, 0, stream>>>(init_h, init_c, h2h, h2l, c2, 1);
    zero_kernel<<<1, 64, 0, stream>>>((unsigned*)zp);

    for (int t = 0; t <= SS; ++t) {
        int do1 = (t < SS) ? 1 : 0;
        int do2 = (t >= 1) ? 1 : 0;
        int t1 = (t < SS) ? t : SS - 1;          // clamped for safe ptr arith
        int u2 = (t >= 1) ? t - 1 : 0;
        const unsigned short* ax1h = xph + (long)t1 * ACT;
        const unsigned short* ax1l = xpl + (long)t1 * ACT;
        const unsigned short* ah1h = (t1 == 0) ? h1h : s1h + (long)(t1 - 1) * ACT;
        const unsigned short* ah1l = (t1 == 0) ? h1l : s1l + (long)(t1 - 1) * ACT;
        unsigned short* ao1h = s1h + (long)t1 * ACT;
        unsigned short* ao1l = s1l + (long)t1 * ACT;
        const unsigned short* ax2h = s1h + (long)u2 * ACT;
        const unsigned short* ax2l = s1l + (long)u2 * ACT;
        const unsigned short* ah2h = (u2 == 0) ? h2h : s2h + (long)(u2 - 1) * ACT;
        const unsigned short* ah2l = (u2 == 0) ? h2l : s2l + (long)(u2 - 1) * ACT;
        unsigned short* ao2h = s2h + (long)u2 * ACT;
        unsigned short* ao2l = s2l + (long)u2 * ACT;
        step_dual<<<512, 256, 0, stream>>>(
            ax1h, ax1l, ah1h, ah1l, c1, ao1h, ao1l,
            ax2h, ax2l, ah2h, ah2l, c2, ao2h, ao2l,
            wh, wl, conv_b, zp, do1, do2);
    }

    pool_kernel<<<SS * BB, 128, 0, stream>>>(s2h, s2l, pooled);
    head_kernel<<<BB * SS, 128, 0, stream>>>(pooled, fc_w, fc_b, fco_w, fco_b, fca_w, fca_b, out);
}

// Round 17
// 1493.792 us; speedup vs baseline: 1.8528x; 1.8528x over previous
//
#include <hip/hip_runtime.h>

// Problem constants
#define BB 4
#define SS 32
#define CC 128
#define HH 16
#define WW 32
#define HID 128
#define DEPTH 2
#define CIN 256           // CC + HID
#define COUT 512          // 4*HID
#define K9 (CIN * 9)      // 2304
#define KH 1152           // per-source K: tap-major k = tap*128 + ch
#define KFULL (2 * KH)    // 2304 = x-part rows then h-part rows
#define HW (HH * WW)      // 512
#define MM (BB * HW)      // 2048
#define ACT (BB * HW * 128) // 262144 = one activation slice (b,hw,ch)

typedef __attribute__((ext_vector_type(4))) float f32x4;
typedef __attribute__((ext_vector_type(8))) short bf16x8;

static __device__ __forceinline__ unsigned short f2bf(float f) {
    union { float f; unsigned u; } v; v.f = f;
    unsigned r = v.u + 0x7FFF + ((v.u >> 16) & 1);   // RNE
    return (unsigned short)(r >> 16);
}
static __device__ __forceinline__ float bf2f(unsigned short h) {
    union { float f; unsigned u; } v; v.u = ((unsigned)h) << 16; return v.f;
}

// ---------------------------------------------------------------------------
// Weight transpose -> separate hi/lo bf16 planes, k-major:
//   wh/wl [DEPTH][COUT_g][KFULL] ushort
// k row: cin<CC -> tap*CC+cin (x block) else KH + tap*HID + (cin-CC) (h block)
// n gate-gathered: n' = (r>>4)*64 + g*16 + (r&15)
// ---------------------------------------------------------------------------
__global__ void transpose_w_kernel(const float* __restrict__ w,
                                   unsigned short* __restrict__ wh,
                                   unsigned short* __restrict__ wl) {
    int idx = blockIdx.x * 256 + threadIdx.x;
    if (idx >= DEPTH * K9 * COUT) return;
    int n = idx % COUT;
    int k = (idx / COUT) % K9;
    int d = idx / (COUT * K9);
    int cin = k / 9, tap = k % 9;
    float v = w[(((long)(d * COUT + n) * CIN + cin) * 9) + tap];
    int row = (cin < CC) ? (tap * CC + cin) : (KH + tap * HID + (cin - CC));
    int g = n >> 7, r = n & 127;
    int ng = (r >> 4) * 64 + g * 16 + (r & 15);
    unsigned short hi = f2bf(v);
    unsigned short lo = f2bf(v - bf2f(hi));
    long o = ((long)d * COUT + ng) * KFULL + row;
    wh[o] = hi;
    wl[o] = lo;
}

// ---------------------------------------------------------------------------
// Pack x [B][S][CC][HW] fp32 -> hi/lo planes [s][b][hw][cc] via LDS transpose.
// grid (SS*BB, HW/64), 256 threads.
// ---------------------------------------------------------------------------
__global__ void pack_x_kernel(const float* __restrict__ x,
                              unsigned* __restrict__ xh32,
                              unsigned* __restrict__ xl32) {
    __shared__ unsigned lh[128 * 33], ll[128 * 33];   // [cc][hw-pair], pad 33
    const int tid = threadIdx.x;
    const int sb  = blockIdx.x;          // s*BB + b
    const int s   = sb >> 2;
    const int b   = sb & 3;
    const int hw0 = blockIdx.y * 64;
    const float* src = x + ((long)(b * SS + s) * CC) * HW;

    #pragma unroll
    for (int it = 0; it < 16; ++it) {
        int cc = it * 8 + (tid >> 5);
        int hw = (tid & 31) * 2;
        float2 v = *(const float2*)&src[cc * HW + hw0 + hw];
        unsigned short h0 = f2bf(v.x), h1 = f2bf(v.y);
        unsigned short l0 = f2bf(v.x - bf2f(h0)), l1 = f2bf(v.y - bf2f(h1));
        lh[cc * 33 + (hw >> 1)] = (unsigned)h0 | ((unsigned)h1 << 16);
        ll[cc * 33 + (hw >> 1)] = (unsigned)l0 | ((unsigned)l1 << 16);
    }
    __syncthreads();
    const unsigned short* lhs = (const unsigned short*)lh;
    const unsigned short* lls = (const unsigned short*)ll;
    #pragma unroll
    for (int it = 0; it < 16; ++it) {
        int hw = it * 4 + (tid >> 6);
        int c2 = tid & 63;               // cc pair
        unsigned short a0 = lhs[(2 * c2) * 66 + hw];
        unsigned short a1 = lhs[(2 * c2 + 1) * 66 + hw];
        unsigned short b0 = lls[(2 * c2) * 66 + hw];
        unsigned short b1 = lls[(2 * c2 + 1) * 66 + hw];
        long o = ((long)sb * HW + hw0 + hw) * 64 + c2;
        xh32[o] = (unsigned)a0 | ((unsigned)a1 << 16);
        xl32[o] = (unsigned)b0 | ((unsigned)b1 << 16);
    }
}

// ---------------------------------------------------------------------------
// Broadcast init_h/init_c[d] into hi/lo h planes ([b][hw][hid]) + fp32 c
// ---------------------------------------------------------------------------
__global__ void init_state_kernel(const float* __restrict__ ih, const float* __restrict__ ic,
                                  unsigned short* __restrict__ hh, unsigned short* __restrict__ hl,
                                  float* __restrict__ c, int d) {
    int idx = blockIdx.x * 256 + threadIdx.x;   // ACT = 262144
    int hid = idx & 127;
    float v = ih[d * HID + hid];
    unsigned short hi = f2bf(v);
    hh[idx] = hi;
    hl[idx] = f2bf(v - bf2f(hi));
    c[idx] = ic[d * HID + hid];
}

// Zero the 256B OOB page (workspace is poisoned 0xAA before timing)
__global__ void zero_kernel(unsigned* __restrict__ zp) { zp[threadIdx.x] = 0u; }

// ---------------------------------------------------------------------------
// DUAL-LAYER fused step kernel — round-15 structure with:
//  (a) conflict-free staging WRITES: each wave stages 16 contiguous rows
//      (8 rows x 8 chunks per ds_write_b128 = 1024B contiguous, 2 lanes/bank)
//      for BOTH the A (activation) and B (weight) tiles;
//  (b) 2-tile-deep register prefetch (sets SA/SB) so global latency has
//      ~2 tile periods to hide.
// M=64, N=64 per wg, 256 thr = 4 waves (2m x 2n of 32x32 from 16x16 frags).
// 8 LDS reads : 12 MFMAs per k-sub. BK=64, one barrier per tile.
// Grid 512 flat, XCD-stable swizzle. K = 36 tiles (18 x-part + 18 h-part).
// ---------------------------------------------------------------------------
__launch_bounds__(256)
__global__ void step_dual(
    const unsigned short* __restrict__ x1h, const unsigned short* __restrict__ x1l,
    const unsigned short* __restrict__ h1h, const unsigned short* __restrict__ h1l,
    float* __restrict__ c1, unsigned short* __restrict__ o1h, unsigned short* __restrict__ o1l,
    const unsigned short* __restrict__ x2h, const unsigned short* __restrict__ x2l,
    const unsigned short* __restrict__ h2h, const unsigned short* __restrict__ h2l,
    float* __restrict__ c2, unsigned short* __restrict__ o2h, unsigned short* __restrict__ o2l,
    const unsigned short* __restrict__ wh, const unsigned short* __restrict__ wl,
    const float* __restrict__ bias, const unsigned short* __restrict__ zp,
    int do1, int do2)
{
    // buf layout (ushort idx): A_hi [0,4096) rows m*64+k, A_lo [4096,8192),
    // B_hi [8192,12288), B_lo [12288,16384). 2 bufs = 64 KB.
    __shared__ __align__(16) unsigned short lds[2][16384];

    const int bid  = blockIdx.x;
    const int xcd  = bid & 7;
    const int q    = bid >> 3;               // 0..63
    const int mblk = q & 31;
    const int pp   = xcd + ((q >> 5) << 3);  // panel 0..15
    const int nblk = pp & 7;
    const int z    = pp >> 3;
    if (z == 0) { if (!do1) return; } else { if (!do2) return; }

    const unsigned short* axh = z ? x2h : x1h;
    const unsigned short* axl = z ? x2l : x1l;
    const unsigned short* ahh = z ? h2h : h1h;
    const unsigned short* ahl = z ? h2l : h1l;
    const unsigned short* wph = wh + (long)z * COUT * KFULL;
    const unsigned short* wpl = wl + (long)z * COUT * KFULL;
    const float* bsel  = bias + z * COUT;
    float* csel        = z ? c2 : c1;
    unsigned short* ohh = z ? o2h : o1h;
    unsigned short* ohl = z ? o2l : o1l;

    const int m0   = mblk * 64;
    const int n0g  = nblk * 64;
    const int hid0 = nblk * 16;
    const int tid  = threadIdx.x;
    const int lane = tid & 63;
    const int wv   = tid >> 6;              // wave 0..3
    const int wm   = (wv >> 1) * 32;        // wave m offset (32x32 tile)
    const int wn   = (wv & 1) * 32;         // wave n offset
    const int b    = m0 >> 9;
    const int hwl  = m0 & 511;
    const int y0   = hwl >> 5;              // first image row (2 rows per wg)

    // --- staging geometry (both A and B): wave wv stages rows 16wv..16wv+15
    // lane: row1 = 16wv + (lane>>3), row2 = row1+8, chunk j = lane&7.
    // LDS slot j holds source chunk j^(row&7); each ds_write_b128 covers
    // 8 rows x 8 chunks = 1024B contiguous -> 2 lanes/bank (free).
    const int row1 = wv * 16 + (lane >> 3);
    const int row2 = row1 + 8;
    const int jch  = lane & 7;
    const int jx1  = jch ^ (row1 & 7);
    const int jx2  = jch ^ (row2 & 7);
    const int sx1  = row1 & 31, sy1b = row1 >> 5;
    const int sx2  = row2 & 31, sy2b = row2 >> 5;
    const long bhw = (long)b * HW;
    const long bro1 = (long)(n0g + row1) * KFULL + jx1 * 8;  // B row bases
    const long bro2 = (long)(n0g + row2) * KFULL + jx2 * 8;
    const int seg1 = row1 * 64 + jch * 8;
    const int seg2 = row2 * 64 + jch * 8;

    // Two register prefetch sets (2-tile-deep pipeline), 8 uint4 each.
#define DECL_SET(S) uint4 S##ah1, S##ah2, S##al1, S##al2, S##bh1, S##bh2, S##bl1, S##bl2
    DECL_SET(SA);
    DECL_SET(SB);
#undef DECL_SET

#define LD(tt, S) do {                                                          \
        const int _tt = (tt);                                                   \
        const long _k0 = (long)_tt * 64;                                        \
        S##bh1 = *(const uint4*)(wph + bro1 + _k0);                             \
        S##bh2 = *(const uint4*)(wph + bro2 + _k0);                             \
        S##bl1 = *(const uint4*)(wpl + bro1 + _k0);                             \
        S##bl2 = *(const uint4*)(wpl + bro2 + _k0);                             \
        int _ks = (_tt < 18) ? _tt : _tt - 18;                                  \
        int _tap = _ks >> 1;                                                    \
        int _c0  = (_ks & 1) << 6;                                              \
        int _ky  = _tap / 3 - 1;                                                \
        int _kx  = _tap - (_tap / 3) * 3 - 1;                                   \
        const unsigned short* _sh = (_tt < 18) ? axh : ahh;                     \
        const unsigned short* _sl = (_tt < 18) ? axl : ahl;                     \
        int _y1 = y0 + sy1b + _ky, _x1 = sx1 + _kx;                             \
        int _y2 = y0 + sy2b + _ky, _x2 = sx2 + _kx;                             \
        bool _o1 = (unsigned)_y1 < (unsigned)HH && (unsigned)_x1 < (unsigned)WW;\
        bool _o2 = (unsigned)_y2 < (unsigned)HH && (unsigned)_x2 < (unsigned)WW;\
        long _a1 = ((bhw + _y1 * WW + _x1) << 7) + _c0 + jx1 * 8;               \
        long _a2 = ((bhw + _y2 * WW + _x2) << 7) + _c0 + jx2 * 8;               \
        S##ah1 = *(const uint4*)(_o1 ? _sh + _a1 : zp);                         \
        S##al1 = *(const uint4*)(_o1 ? _sl + _a1 : zp);                         \
        S##ah2 = *(const uint4*)(_o2 ? _sh + _a2 : zp);                         \
        S##al2 = *(const uint4*)(_o2 ? _sl + _a2 : zp);                         \
    } while (0)

#define COMMIT(S, pb) do {                                                      \
        *(uint4*)&lds[pb][seg1]         = S##ah1;                               \
        *(uint4*)&lds[pb][seg2]         = S##ah2;                               \
        *(uint4*)&lds[pb][4096 + seg1]  = S##al1;                               \
        *(uint4*)&lds[pb][4096 + seg2]  = S##al2;                               \
        *(uint4*)&lds[pb][8192 + seg1]  = S##bh1;                               \
        *(uint4*)&lds[pb][8192 + seg2]  = S##bh2;                               \
        *(uint4*)&lds[pb][12288 + seg1] = S##bl1;                               \
        *(uint4*)&lds[pb][12288 + seg2] = S##bl2;                               \
    } while (0)

    f32x4 acc00 = (f32x4){0.f,0.f,0.f,0.f};
    f32x4 acc01 = (f32x4){0.f,0.f,0.f,0.f};
    f32x4 acc10 = (f32x4){0.f,0.f,0.f,0.f};
    f32x4 acc11 = (f32x4){0.f,0.f,0.f,0.f};

    const int fr  = lane & 15;
    const int kqi = lane >> 4;              // 0..3 (k chunk within sub)
    const int am0 = wm + fr;                // A rows (2 m-frags)
    const int am1 = wm + 16 + fr;
    const int bn0 = wn + fr;                // B rows (2 n-frags)
    const int bn1 = wn + 16 + fr;

#define COMPUTE(P) do {                                                                  \
        const unsigned short* L = &lds[P][0];                                            \
        __builtin_amdgcn_s_setprio(1);                                                   \
        _Pragma("unroll")                                                                \
        for (int s = 0; s < 2; ++s) {                                                    \
            const int ca = s * 4 + kqi;     /* chunk 0..7 */                             \
            bf16x8 ah0 = *(const bf16x8*)&L[am0 * 64 + ((ca ^ (am0 & 7)) << 3)];         \
            bf16x8 ah1 = *(const bf16x8*)&L[am1 * 64 + ((ca ^ (am1 & 7)) << 3)];         \
            bf16x8 al0 = *(const bf16x8*)&L[4096 + am0 * 64 + ((ca ^ (am0 & 7)) << 3)];  \
            bf16x8 al1 = *(const bf16x8*)&L[4096 + am1 * 64 + ((ca ^ (am1 & 7)) << 3)];  \
            bf16x8 bh0 = *(const bf16x8*)&L[8192 + bn0 * 64 + ((ca ^ (bn0 & 7)) << 3)];  \
            bf16x8 bh1 = *(const bf16x8*)&L[8192 + bn1 * 64 + ((ca ^ (bn1 & 7)) << 3)];  \
            bf16x8 bl0 = *(const bf16x8*)&L[12288 + bn0 * 64 + ((ca ^ (bn0 & 7)) << 3)]; \
            bf16x8 bl1 = *(const bf16x8*)&L[12288 + bn1 * 64 + ((ca ^ (bn1 & 7)) << 3)]; \
            acc00 = __builtin_amdgcn_mfma_f32_16x16x32_bf16(ah0, bh0, acc00, 0, 0, 0);   \
            acc01 = __builtin_amdgcn_mfma_f32_16x16x32_bf16(ah0, bh1, acc01, 0, 0, 0);   \
            acc10 = __builtin_amdgcn_mfma_f32_16x16x32_bf16(ah1, bh0, acc10, 0, 0, 0);   \
            acc11 = __builtin_amdgcn_mfma_f32_16x16x32_bf16(ah1, bh1, acc11, 0, 0, 0);   \
            acc00 = __builtin_amdgcn_mfma_f32_16x16x32_bf16(ah0, bl0, acc00, 0, 0, 0);   \
            acc01 = __builtin_amdgcn_mfma_f32_16x16x32_bf16(ah0, bl1, acc01, 0, 0, 0);   \
            acc10 = __builtin_amdgcn_mfma_f32_16x16x32_bf16(ah1, bl0, acc10, 0, 0, 0);   \
            acc11 = __builtin_amdgcn_mfma_f32_16x16x32_bf16(ah1, bl1, acc11, 0, 0, 0);   \
            acc00 = __builtin_amdgcn_mfma_f32_16x16x32_bf16(al0, bh0, acc00, 0, 0, 0);   \
            acc01 = __builtin_amdgcn_mfma_f32_16x16x32_bf16(al0, bh1, acc01, 0, 0, 0);   \
            acc10 = __builtin_amdgcn_mfma_f32_16x16x32_bf16(al1, bh0, acc10, 0, 0, 0);   \
            acc11 = __builtin_amdgcn_mfma_f32_16x16x32_bf16(al1, bh1, acc11, 0, 0, 0);   \
        }                                                                                \
        __builtin_amdgcn_s_setprio(0);                                                   \
    } while (0)

    // Pipeline: SA<-0 committed to buf0; SB<-1; then per tile:
    //   even t: LD(t+2)->SA, COMPUTE(p), COMMIT(SB->1-p), sync
    //   odd  t: LD(t+3)->SB, COMPUTE(p), COMMIT(SA->1-p), sync
    // Loads are issued 2 tiles before consumption -> ~2 tile periods of
    // latency hiding for the (L2-missing) weight fetches.
    LD(0, SA); COMMIT(SA, 0);
    LD(1, SB);
    __syncthreads();

    int p = 0;
    for (int tt = 0; tt < 36; tt += 2) {
        if (tt + 2 < 36) LD(tt + 2, SA);
        COMPUTE(p);
        COMMIT(SB, 1 - p);
        __syncthreads();
        p ^= 1;
        if (tt + 3 < 36) LD(tt + 3, SB);
        COMPUTE(p);
        if (tt + 2 < 36) {
            COMMIT(SA, 1 - p);
            __syncthreads();
            p ^= 1;
        }
    }
    __syncthreads();

#undef LD
#undef COMMIT
#undef COMPUTE

    // --- epilogue: z-tile via LDS (reuse buffer 0), then LSTM cell update ---
    float* zt = (float*)&lds[0][0];         // [64 n_gathered][68 m] = 17.4 KB
    {
        const int rm = (lane >> 4) * 4;
        const int cn = lane & 15;
        *(float4*)&zt[(wn + cn) * 68 + wm + rm]           = *(float4*)&acc00;
        *(float4*)&zt[(wn + 16 + cn) * 68 + wm + rm]      = *(float4*)&acc01;
        *(float4*)&zt[(wn + cn) * 68 + wm + 16 + rm]      = *(float4*)&acc10;
        *(float4*)&zt[(wn + 16 + cn) * 68 + wm + 16 + rm] = *(float4*)&acc11;
    }
    __syncthreads();

    #pragma unroll
    for (int i2 = 0; i2 < 4; ++i2) {        // 1024 cell elems, 4/thread
        int e  = i2 * 256 + tid;
        int m  = e & 63;
        int jh = e >> 6;                    // hid slice 0..15
        float g4[4];
        #pragma unroll
        for (int gi = 0; gi < 4; ++gi)
            g4[gi] = zt[(gi * 16 + jh) * 68 + m] + bsel[gi * 128 + hid0 + jh];
        long idx = ((long)b * HW + hwl + m) * 128 + hid0 + jh;
        float si = 1.f / (1.f + expf(-g4[0]));
        float sf = 1.f / (1.f + expf(-g4[1]));
        float so = 1.f / (1.f + expf(-g4[3]));
        float cs = sf * csel[idx] + si * tanhf(g4[2]);
        float hs = so * tanhf(cs);
        csel[idx] = cs;
        unsigned short hi = f2bf(hs);
        ohh[idx] = hi;
        ohl[idx] = f2bf(hs - bf2f(hi));
    }
}

// ---------------------------------------------------------------------------
// Mean pool over HW: seq2 planes [s][b][hw][hid] -> pooled [(s*BB+b)*HID + j]
// ---------------------------------------------------------------------------
__global__ void pool_kernel(const unsigned short* __restrict__ s2h,
                            const unsigned short* __restrict__ s2l,
                            float* __restrict__ pooled) {
    int bs = blockIdx.x;            // s*BB + b
    int j  = threadIdx.x;           // 0..127
    const unsigned short* ph = s2h + (long)bs * HW * 128 + j;
    const unsigned short* pl = s2l + (long)bs * HW * 128 + j;
    float sum = 0.f;
    #pragma unroll 8
    for (int hw = 0; hw < HW; ++hw)
        sum += bf2f(ph[hw * 128]) + bf2f(pl[hw * 128]);
    pooled[bs * HID + j] = sum * (1.f / HW);
}

// ---------------------------------------------------------------------------
// FC + ReLU + two scalar heads.
// ---------------------------------------------------------------------------
__global__ void head_kernel(const float* __restrict__ pooled,
                            const float* __restrict__ fc_w, const float* __restrict__ fc_b,
                            const float* __restrict__ fco_w, const float* __restrict__ fco_b,
                            const float* __restrict__ fca_w, const float* __restrict__ fca_b,
                            float* __restrict__ out) {
    int bs = blockIdx.x;          // b*S + s
    int b  = bs / SS;
    int s  = bs % SS;
    int j  = threadIdx.x;
    const float* prow = pooled + (long)(s * BB + b) * HID;
    float acc = fc_b[j];
    #pragma unroll 4
    for (int k = 0; k < HID; ++k) acc += fc_w[j * HID + k] * prow[k];
    float f = fmaxf(acc, 0.f);
    __shared__ float ro[128], ra[128];
    ro[j] = f * fco_w[j];
    ra[j] = f * fca_w[j];
    __syncthreads();
    for (int off = 64; off; off >>= 1) {
        if (j < off) { ro[j] += ro[j + off]; ra[j] += ra[j + off]; }
        __syncthreads();
    }
    if (j == 0) {
        out[bs]           = ro[0] + fco_b[0];
        out[BB * SS + bs] = ra[0] + fca_b[0];
    }
}

// ---------------------------------------------------------------------------
extern "C" void kernel_launch(void* const* d_in, const int* in_sizes, int n_in,
                              void* d_out, int out_size, void* d_ws, size_t ws_size,
                              hipStream_t stream) {
    const float* x      = (const float*)d_in[0];
    const float* conv_w = (const float*)d_in[1];
    const float* conv_b = (const float*)d_in[2];
    const float* init_h = (const float*)d_in[3];
    const float* init_c = (const float*)d_in[4];
    const float* fc_w   = (const float*)d_in[5];
    const float* fc_b   = (const float*)d_in[6];
    const float* fco_w  = (const float*)d_in[7];
    const float* fco_b  = (const float*)d_in[8];
    const float* fca_w  = (const float*)d_in[9];
    const float* fca_b  = (const float*)d_in[10];
    float* out = (float*)d_out;

    // Workspace carve-up (ushort planes first, then fp32) — total ~114 MB.
    unsigned short* wh  = (unsigned short*)d_ws;            // 2,359,296
    unsigned short* wl  = wh  + (long)DEPTH * COUT * KFULL; // 2,359,296
    unsigned short* xph = wl  + (long)DEPTH * COUT * KFULL; // SS*ACT = 8,388,608
    unsigned short* xpl = xph + (long)SS * ACT;
    unsigned short* s1h = xpl + (long)SS * ACT;
    unsigned short* s1l = s1h + (long)SS * ACT;
    unsigned short* s2h = s1l + (long)SS * ACT;
    unsigned short* s2l = s2h + (long)SS * ACT;
    unsigned short* h1h = s2l + (long)SS * ACT;             // ACT each
    unsigned short* h1l = h1h + ACT;
    unsigned short* h2h = h1l + ACT;
    unsigned short* h2l = h2h + ACT;
    float* c1     = (float*)(h2l + ACT);                    // ACT f32
    float* c2     = c1 + ACT;
    float* pooled = c2 + ACT;                               // 16,384
    unsigned short* zp = (unsigned short*)(pooled + SS * BB * HID); // 256 B zeros

    transpose_w_kernel<<<(DEPTH * K9 * COUT + 255) / 256, 256, 0, stream>>>(conv_w, wh, wl);
    pack_x_kernel<<<dim3(SS * BB, HW / 64), 256, 0, stream>>>(x, (unsigned*)xph, (unsigned*)xpl);
    init_state_kernel<<<ACT / 256, 256, 0, stream>>>(init_h, init_c, h1h, h1l, c1, 0);
    init_state_kernel<<<ACT / 256, 256, 0, stream>>>(init_h, init_c, h2h, h2l, c2, 1);
    zero_kernel<<<1, 64, 0, stream>>>((unsigned*)zp);

    for (int t = 0; t <= SS; ++t) {
        int do1 = (t < SS) ? 1 : 0;
        int do2 = (t >= 1) ? 1 : 0;
        int t1 = (t < SS) ? t : SS - 1;          // clamped for safe ptr arith
        int u2 = (t >= 1) ? t - 1 : 0;
        const unsigned short* ax1h = xph + (long)t1 * ACT;
        const unsigned short* ax1l = xpl + (long)t1 * ACT;
        const unsigned short* ah1h = (t1 == 0) ? h1h : s1h + (long)(t1 - 1) * ACT;
        const unsigned short* ah1l = (t1 == 0) ? h1l : s1l + (long)(t1 - 1) * ACT;
        unsigned short* ao1h = s1h + (long)t1 * ACT;
        unsigned short* ao1l = s1l + (long)t1 * ACT;
        const unsigned short* ax2h = s1h + (long)u2 * ACT;
        const unsigned short* ax2l = s1l + (long)u2 * ACT;
        const unsigned short* ah2h = (u2 == 0) ? h2h : s2h + (long)(u2 - 1) * ACT;
        const unsigned short* ah2l = (u2 == 0) ? h2l : s2l + (long)(u2 - 1) * ACT;
        unsigned short* ao2h = s2h + (long)u2 * ACT;
        unsigned short* ao2l = s2l + (long)u2 * ACT;
        step_dual<<<512, 256, 0, stream>>>(
            ax1h, ax1l, ah1h, ah1l, c1, ao1h, ao1l,
            ax2h, ax2l, ah2h, ah2l, c2, ao2h, ao2l,
            wh, wl, conv_b, zp, do1, do2);
    }

    pool_kernel<<<SS * BB, 128, 0, stream>>>(s2h, s2l, pooled);
    head_kernel<<<BB * SS, 128, 0, stream>>>(pooled, fc_w, fc_b, fco_w, fco_b, fca_w, fca_b, out);
}

// Round 18
// 1144.188 us; speedup vs baseline: 2.4189x; 1.3055x over previous
//
#include <hip/hip_runtime.h>

// Problem constants
#define BB 4
#define SS 32
#define CC 128
#define HH 16
#define WW 32
#define HID 128
#define DEPTH 2
#define CIN 256           // CC + HID
#define COUT 512          // 4*HID
#define K9 (CIN * 9)      // 2304
#define KH 1152           // per-source K: tap-major k = tap*128 + ch
#define KFULL (2 * KH)    // 2304 = x-part rows then h-part rows
#define HW (HH * WW)      // 512
#define MM (BB * HW)      // 2048
#define ACT (BB * HW * 128) // 262144 = one activation slice (b,hw,ch)

typedef __attribute__((ext_vector_type(4))) float f32x4;
typedef __attribute__((ext_vector_type(8))) short bf16x8;

static __device__ __forceinline__ unsigned short f2bf(float f) {
    union { float f; unsigned u; } v; v.f = f;
    unsigned r = v.u + 0x7FFF + ((v.u >> 16) & 1);   // RNE
    return (unsigned short)(r >> 16);
}
static __device__ __forceinline__ float bf2f(unsigned short h) {
    union { float f; unsigned u; } v; v.u = ((unsigned)h) << 16; return v.f;
}

// ---------------------------------------------------------------------------
// Weight transpose -> separate hi/lo bf16 planes (weights KEEP the exact
// hi/lo split; activations are hi-only), k-major:
//   wh/wl [DEPTH][COUT_g][KFULL] ushort
// k row: cin<CC -> tap*CC+cin (x block) else KH + tap*HID + (cin-CC) (h block)
// n gate-gathered: n' = (r>>4)*64 + g*16 + (r&15)
// ---------------------------------------------------------------------------
__global__ void transpose_w_kernel(const float* __restrict__ w,
                                   unsigned short* __restrict__ wh,
                                   unsigned short* __restrict__ wl) {
    int idx = blockIdx.x * 256 + threadIdx.x;
    if (idx >= DEPTH * K9 * COUT) return;
    int n = idx % COUT;
    int k = (idx / COUT) % K9;
    int d = idx / (COUT * K9);
    int cin = k / 9, tap = k % 9;
    float v = w[(((long)(d * COUT + n) * CIN + cin) * 9) + tap];
    int row = (cin < CC) ? (tap * CC + cin) : (KH + tap * HID + (cin - CC));
    int g = n >> 7, r = n & 127;
    int ng = (r >> 4) * 64 + g * 16 + (r & 15);
    unsigned short hi = f2bf(v);
    unsigned short lo = f2bf(v - bf2f(hi));
    long o = ((long)d * COUT + ng) * KFULL + row;
    wh[o] = hi;
    wl[o] = lo;
}

// ---------------------------------------------------------------------------
// Pack x [B][S][CC][HW] fp32 -> hi bf16 plane [s][b][hw][cc] via LDS
// transpose. grid (SS*BB, HW/64), 256 threads.
// ---------------------------------------------------------------------------
__global__ void pack_x_kernel(const float* __restrict__ x,
                              unsigned* __restrict__ xh32) {
    __shared__ unsigned lh[128 * 33];    // [cc][hw-pair], pad 33
    const int tid = threadIdx.x;
    const int sb  = blockIdx.x;          // s*BB + b
    const int s   = sb >> 2;
    const int b   = sb & 3;
    const int hw0 = blockIdx.y * 64;
    const float* src = x + ((long)(b * SS + s) * CC) * HW;

    #pragma unroll
    for (int it = 0; it < 16; ++it) {
        int cc = it * 8 + (tid >> 5);
        int hw = (tid & 31) * 2;
        float2 v = *(const float2*)&src[cc * HW + hw0 + hw];
        unsigned short h0 = f2bf(v.x), h1 = f2bf(v.y);
        lh[cc * 33 + (hw >> 1)] = (unsigned)h0 | ((unsigned)h1 << 16);
    }
    __syncthreads();
    const unsigned short* lhs = (const unsigned short*)lh;
    #pragma unroll
    for (int it = 0; it < 16; ++it) {
        int hw = it * 4 + (tid >> 6);
        int c2 = tid & 63;               // cc pair
        unsigned short a0 = lhs[(2 * c2) * 66 + hw];
        unsigned short a1 = lhs[(2 * c2 + 1) * 66 + hw];
        long o = ((long)sb * HW + hw0 + hw) * 64 + c2;
        xh32[o] = (unsigned)a0 | ((unsigned)a1 << 16);
    }
}

// ---------------------------------------------------------------------------
// Broadcast init_h/init_c[d] into hi h plane ([b][hw][hid]) + fp32 c
// ---------------------------------------------------------------------------
__global__ void init_state_kernel(const float* __restrict__ ih, const float* __restrict__ ic,
                                  unsigned short* __restrict__ hh,
                                  float* __restrict__ c, int d) {
    int idx = blockIdx.x * 256 + threadIdx.x;   // ACT = 262144
    int hid = idx & 127;
    hh[idx] = f2bf(ih[d * HID + hid]);
    c[idx] = ic[d * HID + hid];
}

// Zero the 256B OOB page (workspace is poisoned 0xAA before timing)
__global__ void zero_kernel(unsigned* __restrict__ zp) { zp[threadIdx.x] = 0u; }

// ---------------------------------------------------------------------------
// DUAL-LAYER fused step kernel — activation hi-only, weight hi/lo (bf16x2):
//   z = ah*wh + ah*wl. Per wave-sub: 6 LDS reads -> 8 MFMAs.
// LDS per wg-tile: reads 48 KB, writes 24 KB (was 64/32). 48 KB LDS/wg.
// Conflict-free staging writes (1024B-contiguous), XOR-swizzled reads,
// 2-tile-deep register prefetch, one barrier per tile, setprio on MFMA.
// M=64, N=64 per wg, 256 thr = 4 waves (2m x 2n of 32x32 from 16x16 frags).
// Grid 512 flat, XCD-stable swizzle. K = 36 tiles (18 x-part + 18 h-part).
// ---------------------------------------------------------------------------
__launch_bounds__(256)
__global__ void step_dual(
    const unsigned short* __restrict__ x1h, const unsigned short* __restrict__ h1h,
    float* __restrict__ c1, unsigned short* __restrict__ o1h,
    const unsigned short* __restrict__ x2h, const unsigned short* __restrict__ h2h,
    float* __restrict__ c2, unsigned short* __restrict__ o2h,
    const unsigned short* __restrict__ wh, const unsigned short* __restrict__ wl,
    const float* __restrict__ bias, const unsigned short* __restrict__ zp,
    int do1, int do2)
{
    // buf layout (ushort idx): A_hi [0,4096) rows m*64+k,
    // B_hi [4096,8192), B_lo [8192,12288). 2 bufs = 48 KB.
    __shared__ __align__(16) unsigned short lds[2][12288];

    const int bid  = blockIdx.x;
    const int xcd  = bid & 7;
    const int q    = bid >> 3;               // 0..63
    const int mblk = q & 31;
    const int pp   = xcd + ((q >> 5) << 3);  // panel 0..15
    const int nblk = pp & 7;
    const int z    = pp >> 3;
    if (z == 0) { if (!do1) return; } else { if (!do2) return; }

    const unsigned short* axh = z ? x2h : x1h;
    const unsigned short* ahh = z ? h2h : h1h;
    const unsigned short* wph = wh + (long)z * COUT * KFULL;
    const unsigned short* wpl = wl + (long)z * COUT * KFULL;
    const float* bsel  = bias + z * COUT;
    float* csel        = z ? c2 : c1;
    unsigned short* ohh = z ? o2h : o1h;

    const int m0   = mblk * 64;
    const int n0g  = nblk * 64;
    const int hid0 = nblk * 16;
    const int tid  = threadIdx.x;
    const int lane = tid & 63;
    const int wv   = tid >> 6;              // wave 0..3
    const int wm   = (wv >> 1) * 32;        // wave m offset (32x32 tile)
    const int wn   = (wv & 1) * 32;         // wave n offset
    const int b    = m0 >> 9;
    const int hwl  = m0 & 511;
    const int y0   = hwl >> 5;              // first image row (2 rows per wg)

    // staging geometry: wave wv stages rows 16wv..16wv+15 of each plane.
    // lane: row1 = 16wv + (lane>>3), row2 = row1+8, chunk j = lane&7.
    // LDS slot j holds source chunk j^(row&7); each ds_write_b128 covers
    // 8 rows x 8 chunks = 1024B contiguous -> 2 lanes/bank (free).
    const int row1 = wv * 16 + (lane >> 3);
    const int row2 = row1 + 8;
    const int jch  = lane & 7;
    const int jx1  = jch ^ (row1 & 7);
    const int jx2  = jch ^ (row2 & 7);
    const int sx1  = row1 & 31, sy1b = row1 >> 5;
    const int sx2  = row2 & 31, sy2b = row2 >> 5;
    const long bhw = (long)b * HW;
    const long bro1 = (long)(n0g + row1) * KFULL + jx1 * 8;  // B row bases
    const long bro2 = (long)(n0g + row2) * KFULL + jx2 * 8;
    const int seg1 = row1 * 64 + jch * 8;
    const int seg2 = row2 * 64 + jch * 8;

    // Two register prefetch sets (2-tile-deep pipeline), 6 uint4 each.
#define DECL_SET(S) uint4 S##ah1, S##ah2, S##bh1, S##bh2, S##bl1, S##bl2
    DECL_SET(SA);
    DECL_SET(SB);
#undef DECL_SET

#define LD(tt, S) do {                                                          \
        const int _tt = (tt);                                                   \
        const long _k0 = (long)_tt * 64;                                        \
        S##bh1 = *(const uint4*)(wph + bro1 + _k0);                             \
        S##bh2 = *(const uint4*)(wph + bro2 + _k0);                             \
        S##bl1 = *(const uint4*)(wpl + bro1 + _k0);                             \
        S##bl2 = *(const uint4*)(wpl + bro2 + _k0);                             \
        int _ks = (_tt < 18) ? _tt : _tt - 18;                                  \
        int _tap = _ks >> 1;                                                    \
        int _c0  = (_ks & 1) << 6;                                              \
        int _ky  = _tap / 3 - 1;                                                \
        int _kx  = _tap - (_tap / 3) * 3 - 1;                                   \
        const unsigned short* _sh = (_tt < 18) ? axh : ahh;                     \
        int _y1 = y0 + sy1b + _ky, _x1 = sx1 + _kx;                             \
        int _y2 = y0 + sy2b + _ky, _x2 = sx2 + _kx;                             \
        bool _o1 = (unsigned)_y1 < (unsigned)HH && (unsigned)_x1 < (unsigned)WW;\
        bool _o2 = (unsigned)_y2 < (unsigned)HH && (unsigned)_x2 < (unsigned)WW;\
        long _a1 = ((bhw + _y1 * WW + _x1) << 7) + _c0 + jx1 * 8;               \
        long _a2 = ((bhw + _y2 * WW + _x2) << 7) + _c0 + jx2 * 8;               \
        S##ah1 = *(const uint4*)(_o1 ? _sh + _a1 : zp);                         \
        S##ah2 = *(const uint4*)(_o2 ? _sh + _a2 : zp);                         \
    } while (0)

#define COMMIT(S, pb) do {                                                      \
        *(uint4*)&lds[pb][seg1]         = S##ah1;                               \
        *(uint4*)&lds[pb][seg2]         = S##ah2;                               \
        *(uint4*)&lds[pb][4096 + seg1]  = S##bh1;                               \
        *(uint4*)&lds[pb][4096 + seg2]  = S##bh2;                               \
        *(uint4*)&lds[pb][8192 + seg1]  = S##bl1;                               \
        *(uint4*)&lds[pb][8192 + seg2]  = S##bl2;                               \
    } while (0)

    f32x4 acc00 = (f32x4){0.f,0.f,0.f,0.f};
    f32x4 acc01 = (f32x4){0.f,0.f,0.f,0.f};
    f32x4 acc10 = (f32x4){0.f,0.f,0.f,0.f};
    f32x4 acc11 = (f32x4){0.f,0.f,0.f,0.f};

    const int fr  = lane & 15;
    const int kqi = lane >> 4;              // 0..3 (k chunk within sub)
    const int am0 = wm + fr;                // A rows (2 m-frags)
    const int am1 = wm + 16 + fr;
    const int bn0 = wn + fr;                // B rows (2 n-frags)
    const int bn1 = wn + 16 + fr;

#define COMPUTE(P) do {                                                                  \
        const unsigned short* L = &lds[P][0];                                            \
        __builtin_amdgcn_s_setprio(1);                                                   \
        _Pragma("unroll")                                                                \
        for (int s = 0; s < 2; ++s) {                                                    \
            const int ca = s * 4 + kqi;     /* chunk 0..7 */                             \
            bf16x8 fa0 = *(const bf16x8*)&L[am0 * 64 + ((ca ^ (am0 & 7)) << 3)];         \
            bf16x8 fa1 = *(const bf16x8*)&L[am1 * 64 + ((ca ^ (am1 & 7)) << 3)];         \
            bf16x8 fbh0 = *(const bf16x8*)&L[4096 + bn0 * 64 + ((ca ^ (bn0 & 7)) << 3)]; \
            bf16x8 fbh1 = *(const bf16x8*)&L[4096 + bn1 * 64 + ((ca ^ (bn1 & 7)) << 3)]; \
            bf16x8 fbl0 = *(const bf16x8*)&L[8192 + bn0 * 64 + ((ca ^ (bn0 & 7)) << 3)]; \
            bf16x8 fbl1 = *(const bf16x8*)&L[8192 + bn1 * 64 + ((ca ^ (bn1 & 7)) << 3)]; \
            acc00 = __builtin_amdgcn_mfma_f32_16x16x32_bf16(fa0, fbh0, acc00, 0, 0, 0);  \
            acc01 = __builtin_amdgcn_mfma_f32_16x16x32_bf16(fa0, fbh1, acc01, 0, 0, 0);  \
            acc10 = __builtin_amdgcn_mfma_f32_16x16x32_bf16(fa1, fbh0, acc10, 0, 0, 0);  \
            acc11 = __builtin_amdgcn_mfma_f32_16x16x32_bf16(fa1, fbh1, acc11, 0, 0, 0);  \
            acc00 = __builtin_amdgcn_mfma_f32_16x16x32_bf16(fa0, fbl0, acc00, 0, 0, 0);  \
            acc01 = __builtin_amdgcn_mfma_f32_16x16x32_bf16(fa0, fbl1, acc01, 0, 0, 0);  \
            acc10 = __builtin_amdgcn_mfma_f32_16x16x32_bf16(fa1, fbl0, acc10, 0, 0, 0);  \
            acc11 = __builtin_amdgcn_mfma_f32_16x16x32_bf16(fa1, fbl1, acc11, 0, 0, 0);  \
        }                                                                                \
        __builtin_amdgcn_s_setprio(0);                                                   \
    } while (0)

    // Pipeline: loads issued 2 tiles ahead of consumption.
    LD(0, SA); COMMIT(SA, 0);
    LD(1, SB);
    __syncthreads();

    int p = 0;
    for (int tt = 0; tt < 36; tt += 2) {
        if (tt + 2 < 36) LD(tt + 2, SA);
        COMPUTE(p);
        COMMIT(SB, 1 - p);
        __syncthreads();
        p ^= 1;
        if (tt + 3 < 36) LD(tt + 3, SB);
        COMPUTE(p);
        if (tt + 2 < 36) {
            COMMIT(SA, 1 - p);
            __syncthreads();
            p ^= 1;
        }
    }
    __syncthreads();

#undef LD
#undef COMMIT
#undef COMPUTE

    // --- epilogue: z-tile via LDS (reuse buffer 0), then LSTM cell update ---
    float* zt = (float*)&lds[0][0];         // [64 n_gathered][68 m] = 17.4 KB
    {
        const int rm = (lane >> 4) * 4;
        const int cn = lane & 15;
        *(float4*)&zt[(wn + cn) * 68 + wm + rm]           = *(float4*)&acc00;
        *(float4*)&zt[(wn + 16 + cn) * 68 + wm + rm]      = *(float4*)&acc01;
        *(float4*)&zt[(wn + cn) * 68 + wm + 16 + rm]      = *(float4*)&acc10;
        *(float4*)&zt[(wn + 16 + cn) * 68 + wm + 16 + rm] = *(float4*)&acc11;
    }
    __syncthreads();

    #pragma unroll
    for (int i2 = 0; i2 < 4; ++i2) {        // 1024 cell elems, 4/thread
        int e  = i2 * 256 + tid;
        int m  = e & 63;
        int jh = e >> 6;                    // hid slice 0..15
        float g4[4];
        #pragma unroll
        for (int gi = 0; gi < 4; ++gi)
            g4[gi] = zt[(gi * 16 + jh) * 68 + m] + bsel[gi * 128 + hid0 + jh];
        long idx = ((long)b * HW + hwl + m) * 128 + hid0 + jh;
        float si = 1.f / (1.f + expf(-g4[0]));
        float sf = 1.f / (1.f + expf(-g4[1]));
        float so = 1.f / (1.f + expf(-g4[3]));
        float cs = sf * csel[idx] + si * tanhf(g4[2]);
        float hs = so * tanhf(cs);
        csel[idx] = cs;
        ohh[idx] = f2bf(hs);
    }
}

// ---------------------------------------------------------------------------
// Mean pool over HW: seq2 hi plane [s][b][hw][hid] -> pooled
// ---------------------------------------------------------------------------
__global__ void pool_kernel(const unsigned short* __restrict__ s2h,
                            float* __restrict__ pooled) {
    int bs = blockIdx.x;            // s*BB + b
    int j  = threadIdx.x;           // 0..127
    const unsigned short* ph = s2h + (long)bs * HW * 128 + j;
    float sum = 0.f;
    #pragma unroll 8
    for (int hw = 0; hw < HW; ++hw)
        sum += bf2f(ph[hw * 128]);
    pooled[bs * HID + j] = sum * (1.f / HW);
}

// ---------------------------------------------------------------------------
// FC + ReLU + two scalar heads.
// ---------------------------------------------------------------------------
__global__ void head_kernel(const float* __restrict__ pooled,
                            const float* __restrict__ fc_w, const float* __restrict__ fc_b,
                            const float* __restrict__ fco_w, const float* __restrict__ fco_b,
                            const float* __restrict__ fca_w, const float* __restrict__ fca_b,
                            float* __restrict__ out) {
    int bs = blockIdx.x;          // b*S + s
    int b  = bs / SS;
    int s  = bs % SS;
    int j  = threadIdx.x;
    const float* prow = pooled + (long)(s * BB + b) * HID;
    float acc = fc_b[j];
    #pragma unroll 4
    for (int k = 0; k < HID; ++k) acc += fc_w[j * HID + k] * prow[k];
    float f = fmaxf(acc, 0.f);
    __shared__ float ro[128], ra[128];
    ro[j] = f * fco_w[j];
    ra[j] = f * fca_w[j];
    __syncthreads();
    for (int off = 64; off; off >>= 1) {
        if (j < off) { ro[j] += ro[j + off]; ra[j] += ra[j + off]; }
        __syncthreads();
    }
    if (j == 0) {
        out[bs]           = ro[0] + fco_b[0];
        out[BB * SS + bs] = ra[0] + fca_b[0];
    }
}

// ---------------------------------------------------------------------------
extern "C" void kernel_launch(void* const* d_in, const int* in_sizes, int n_in,
                              void* d_out, int out_size, void* d_ws, size_t ws_size,
                              hipStream_t stream) {
    const float* x      = (const float*)d_in[0];
    const float* conv_w = (const float*)d_in[1];
    const float* conv_b = (const float*)d_in[2];
    const float* init_h = (const float*)d_in[3];
    const float* init_c = (const float*)d_in[4];
    const float* fc_w   = (const float*)d_in[5];
    const float* fc_b   = (const float*)d_in[6];
    const float* fco_w  = (const float*)d_in[7];
    const float* fco_b  = (const float*)d_in[8];
    const float* fca_w  = (const float*)d_in[9];
    const float* fca_b  = (const float*)d_in[10];
    float* out = (float*)d_out;

    // Workspace carve-up — total ~65 MB.
    unsigned short* wh  = (unsigned short*)d_ws;            // 2,359,296
    unsigned short* wl  = wh  + (long)DEPTH * COUT * KFULL; // 2,359,296
    unsigned short* xph = wl  + (long)DEPTH * COUT * KFULL; // SS*ACT = 8,388,608
    unsigned short* s1h = xph + (long)SS * ACT;
    unsigned short* s2h = s1h + (long)SS * ACT;
    unsigned short* h1h = s2h + (long)SS * ACT;             // ACT each
    unsigned short* h2h = h1h + ACT;
    float* c1     = (float*)(h2h + ACT);                    // ACT f32
    float* c2     = c1 + ACT;
    float* pooled = c2 + ACT;                               // 16,384
    unsigned short* zp = (unsigned short*)(pooled + SS * BB * HID); // 256 B zeros

    transpose_w_kernel<<<(DEPTH * K9 * COUT + 255) / 256, 256, 0, stream>>>(conv_w, wh, wl);
    pack_x_kernel<<<dim3(SS * BB, HW / 64), 256, 0, stream>>>(x, (unsigned*)xph);
    init_state_kernel<<<ACT / 256, 256, 0, stream>>>(init_h, init_c, h1h, c1, 0);
    init_state_kernel<<<ACT / 256, 256, 0, stream>>>(init_h, init_c, h2h, c2, 1);
    zero_kernel<<<1, 64, 0, stream>>>((unsigned*)zp);

    for (int t = 0; t <= SS; ++t) {
        int do1 = (t < SS) ? 1 : 0;
        int do2 = (t >= 1) ? 1 : 0;
        int t1 = (t < SS) ? t : SS - 1;          // clamped for safe ptr arith
        int u2 = (t >= 1) ? t - 1 : 0;
        const unsigned short* ax1h = xph + (long)t1 * ACT;
        const unsigned short* ah1h = (t1 == 0) ? h1h : s1h + (long)(t1 - 1) * ACT;
        unsigned short* ao1h = s1h + (long)t1 * ACT;
        const unsigned short* ax2h = s1h + (long)u2 * ACT;
        const unsigned short* ah2h = (u2 == 0) ? h2h : s2h + (long)(u2 - 1) * ACT;
        unsigned short* ao2h = s2h + (long)u2 * ACT;
        step_dual<<<512, 256, 0, stream>>>(
            ax1h, ah1h, c1, ao1h,
            ax2h, ah2h, c2, ao2h,
            wh, wl, conv_b, zp, do1, do2);
    }

    pool_kernel<<<SS * BB, 128, 0, stream>>>(s2h, pooled);
    head_kernel<<<BB * SS, 128, 0, stream>>>(pooled, fc_w, fc_b, fco_w, fco_b, fca_w, fca_b, out);
}

// Round 19
// 916.995 us; speedup vs baseline: 3.0182x; 1.2478x over previous
//
#include <hip/hip_runtime.h>

// Problem constants
#define BB 4
#define SS 32
#define CC 128
#define HH 16
#define WW 32
#define HID 128
#define DEPTH 2
#define CIN 256           // CC + HID
#define COUT 512          // 4*HID
#define K9 (CIN * 9)      // 2304
#define KH 1152           // per-source K: tap-major k = tap*128 + ch
#define KFULL (2 * KH)    // 2304 = x-part rows then h-part rows
#define HW (HH * WW)      // 512
#define MM (BB * HW)      // 2048
#define ACT (BB * HW * 128) // 262144 = one activation slice (b,hw,ch)

typedef __attribute__((ext_vector_type(4))) float f32x4;
typedef __attribute__((ext_vector_type(8))) short bf16x8;

static __device__ __forceinline__ unsigned short f2bf(float f) {
    union { float f; unsigned u; } v; v.f = f;
    unsigned r = v.u + 0x7FFF + ((v.u >> 16) & 1);   // RNE
    return (unsigned short)(r >> 16);
}
static __device__ __forceinline__ float bf2f(unsigned short h) {
    union { float f; unsigned u; } v; v.u = ((unsigned)h) << 16; return v.f;
}

// ---------------------------------------------------------------------------
// Weight transpose -> single bf16 plane (RNE), k-major:
//   wh [DEPTH][COUT_g][KFULL] ushort
// k row: cin<CC -> tap*CC+cin (x block) else KH + tap*HID + (cin-CC) (h block)
// n gate-gathered: n' = (r>>4)*64 + g*16 + (r&15)
// ---------------------------------------------------------------------------
__global__ void transpose_w_kernel(const float* __restrict__ w,
                                   unsigned short* __restrict__ wh) {
    int idx = blockIdx.x * 256 + threadIdx.x;
    if (idx >= DEPTH * K9 * COUT) return;
    int n = idx % COUT;
    int k = (idx / COUT) % K9;
    int d = idx / (COUT * K9);
    int cin = k / 9, tap = k % 9;
    float v = w[(((long)(d * COUT + n) * CIN + cin) * 9) + tap];
    int row = (cin < CC) ? (tap * CC + cin) : (KH + tap * HID + (cin - CC));
    int g = n >> 7, r = n & 127;
    int ng = (r >> 4) * 64 + g * 16 + (r & 15);
    wh[((long)d * COUT + ng) * KFULL + row] = f2bf(v);
}

// ---------------------------------------------------------------------------
// Pack x [B][S][CC][HW] fp32 -> hi bf16 plane [s][b][hw][cc] via LDS
// transpose. grid (SS*BB, HW/64), 256 threads.
// ---------------------------------------------------------------------------
__global__ void pack_x_kernel(const float* __restrict__ x,
                              unsigned* __restrict__ xh32) {
    __shared__ unsigned lh[128 * 33];    // [cc][hw-pair], pad 33
    const int tid = threadIdx.x;
    const int sb  = blockIdx.x;          // s*BB + b
    const int s   = sb >> 2;
    const int b   = sb & 3;
    const int hw0 = blockIdx.y * 64;
    const float* src = x + ((long)(b * SS + s) * CC) * HW;

    #pragma unroll
    for (int it = 0; it < 16; ++it) {
        int cc = it * 8 + (tid >> 5);
        int hw = (tid & 31) * 2;
        float2 v = *(const float2*)&src[cc * HW + hw0 + hw];
        unsigned short h0 = f2bf(v.x), h1 = f2bf(v.y);
        lh[cc * 33 + (hw >> 1)] = (unsigned)h0 | ((unsigned)h1 << 16);
    }
    __syncthreads();
    const unsigned short* lhs = (const unsigned short*)lh;
    #pragma unroll
    for (int it = 0; it < 16; ++it) {
        int hw = it * 4 + (tid >> 6);
        int c2 = tid & 63;               // cc pair
        unsigned short a0 = lhs[(2 * c2) * 66 + hw];
        unsigned short a1 = lhs[(2 * c2 + 1) * 66 + hw];
        long o = ((long)sb * HW + hw0 + hw) * 64 + c2;
        xh32[o] = (unsigned)a0 | ((unsigned)a1 << 16);
    }
}

// ---------------------------------------------------------------------------
// Broadcast init_h/init_c[d] into hi h plane ([b][hw][hid]) + fp32 c
// ---------------------------------------------------------------------------
__global__ void init_state_kernel(const float* __restrict__ ih, const float* __restrict__ ic,
                                  unsigned short* __restrict__ hh,
                                  float* __restrict__ c, int d) {
    int idx = blockIdx.x * 256 + threadIdx.x;   // ACT = 262144
    int hid = idx & 127;
    hh[idx] = f2bf(ih[d * HID + hid]);
    c[idx] = ic[d * HID + hid];
}

// Zero the 256B OOB page (workspace is poisoned 0xAA before timing)
__global__ void zero_kernel(unsigned* __restrict__ zp) { zp[threadIdx.x] = 0u; }

// ---------------------------------------------------------------------------
// DUAL-LAYER fused step kernel — activation bf16, weight bf16 (plain):
//   z = ah*wh. Per wave-sub: 4 LDS reads -> 4 MFMAs.
// LDS per wg-tile: reads 32 KB, writes 16 KB. 32 KB LDS/wg.
// Conflict-free staging writes (1024B-contiguous), XOR-swizzled reads,
// 2-tile-deep register prefetch, one barrier per tile, setprio on MFMA.
// M=64, N=64 per wg, 256 thr = 4 waves (2m x 2n of 32x32 from 16x16 frags).
// Grid 512 flat, XCD-stable swizzle. K = 36 tiles (18 x-part + 18 h-part).
// ---------------------------------------------------------------------------
__launch_bounds__(256)
__global__ void step_dual(
    const unsigned short* __restrict__ x1h, const unsigned short* __restrict__ h1h,
    float* __restrict__ c1, unsigned short* __restrict__ o1h,
    const unsigned short* __restrict__ x2h, const unsigned short* __restrict__ h2h,
    float* __restrict__ c2, unsigned short* __restrict__ o2h,
    const unsigned short* __restrict__ wh,
    const float* __restrict__ bias, const unsigned short* __restrict__ zp,
    int do1, int do2)
{
    // buf layout (ushort idx): A_hi [0,4096) rows m*64+k, B_hi [4096,8192).
    // 2 bufs = 32 KB.
    __shared__ __align__(16) unsigned short lds[2][8192];

    const int bid  = blockIdx.x;
    const int xcd  = bid & 7;
    const int q    = bid >> 3;               // 0..63
    const int mblk = q & 31;
    const int pp   = xcd + ((q >> 5) << 3);  // panel 0..15
    const int nblk = pp & 7;
    const int z    = pp >> 3;
    if (z == 0) { if (!do1) return; } else { if (!do2) return; }

    const unsigned short* axh = z ? x2h : x1h;
    const unsigned short* ahh = z ? h2h : h1h;
    const unsigned short* wph = wh + (long)z * COUT * KFULL;
    const float* bsel  = bias + z * COUT;
    float* csel        = z ? c2 : c1;
    unsigned short* ohh = z ? o2h : o1h;

    const int m0   = mblk * 64;
    const int n0g  = nblk * 64;
    const int hid0 = nblk * 16;
    const int tid  = threadIdx.x;
    const int lane = tid & 63;
    const int wv   = tid >> 6;              // wave 0..3
    const int wm   = (wv >> 1) * 32;        // wave m offset (32x32 tile)
    const int wn   = (wv & 1) * 32;         // wave n offset
    const int b    = m0 >> 9;
    const int hwl  = m0 & 511;
    const int y0   = hwl >> 5;              // first image row (2 rows per wg)

    // staging geometry: wave wv stages rows 16wv..16wv+15 of each plane.
    // lane: row1 = 16wv + (lane>>3), row2 = row1+8, chunk j = lane&7.
    // LDS slot j holds source chunk j^(row&7); each ds_write_b128 covers
    // 8 rows x 8 chunks = 1024B contiguous -> 2 lanes/bank (free).
    const int row1 = wv * 16 + (lane >> 3);
    const int row2 = row1 + 8;
    const int jch  = lane & 7;
    const int jx1  = jch ^ (row1 & 7);
    const int jx2  = jch ^ (row2 & 7);
    const int sx1  = row1 & 31, sy1b = row1 >> 5;
    const int sx2  = row2 & 31, sy2b = row2 >> 5;
    const long bhw = (long)b * HW;
    const long bro1 = (long)(n0g + row1) * KFULL + jx1 * 8;  // B row bases
    const long bro2 = (long)(n0g + row2) * KFULL + jx2 * 8;
    const int seg1 = row1 * 64 + jch * 8;
    const int seg2 = row2 * 64 + jch * 8;

    // Two register prefetch sets (2-tile-deep pipeline), 4 uint4 each.
#define DECL_SET(S) uint4 S##ah1, S##ah2, S##bh1, S##bh2
    DECL_SET(SA);
    DECL_SET(SB);
#undef DECL_SET

#define LD(tt, S) do {                                                          \
        const int _tt = (tt);                                                   \
        const long _k0 = (long)_tt * 64;                                        \
        S##bh1 = *(const uint4*)(wph + bro1 + _k0);                             \
        S##bh2 = *(const uint4*)(wph + bro2 + _k0);                             \
        int _ks = (_tt < 18) ? _tt : _tt - 18;                                  \
        int _tap = _ks >> 1;                                                    \
        int _c0  = (_ks & 1) << 6;                                              \
        int _ky  = _tap / 3 - 1;                                                \
        int _kx  = _tap - (_tap / 3) * 3 - 1;                                   \
        const unsigned short* _sh = (_tt < 18) ? axh : ahh;                     \
        int _y1 = y0 + sy1b + _ky, _x1 = sx1 + _kx;                             \
        int _y2 = y0 + sy2b + _ky, _x2 = sx2 + _kx;                             \
        bool _o1 = (unsigned)_y1 < (unsigned)HH && (unsigned)_x1 < (unsigned)WW;\
        bool _o2 = (unsigned)_y2 < (unsigned)HH && (unsigned)_x2 < (unsigned)WW;\
        long _a1 = ((bhw + _y1 * WW + _x1) << 7) + _c0 + jx1 * 8;               \
        long _a2 = ((bhw + _y2 * WW + _x2) << 7) + _c0 + jx2 * 8;               \
        S##ah1 = *(const uint4*)(_o1 ? _sh + _a1 : zp);                         \
        S##ah2 = *(const uint4*)(_o2 ? _sh + _a2 : zp);                         \
    } while (0)

#define COMMIT(S, pb) do {                                                      \
        *(uint4*)&lds[pb][seg1]         = S##ah1;                               \
        *(uint4*)&lds[pb][seg2]         = S##ah2;                               \
        *(uint4*)&lds[pb][4096 + seg1]  = S##bh1;                               \
        *(uint4*)&lds[pb][4096 + seg2]  = S##bh2;                               \
    } while (0)

    f32x4 acc00 = (f32x4){0.f,0.f,0.f,0.f};
    f32x4 acc01 = (f32x4){0.f,0.f,0.f,0.f};
    f32x4 acc10 = (f32x4){0.f,0.f,0.f,0.f};
    f32x4 acc11 = (f32x4){0.f,0.f,0.f,0.f};

    const int fr  = lane & 15;
    const int kqi = lane >> 4;              // 0..3 (k chunk within sub)
    const int am0 = wm + fr;                // A rows (2 m-frags)
    const int am1 = wm + 16 + fr;
    const int bn0 = wn + fr;                // B rows (2 n-frags)
    const int bn1 = wn + 16 + fr;

#define COMPUTE(P) do {                                                                  \
        const unsigned short* L = &lds[P][0];                                            \
        __builtin_amdgcn_s_setprio(1);                                                   \
        _Pragma("unroll")                                                                \
        for (int s = 0; s < 2; ++s) {                                                    \
            const int ca = s * 4 + kqi;     /* chunk 0..7 */                             \
            bf16x8 fa0 = *(const bf16x8*)&L[am0 * 64 + ((ca ^ (am0 & 7)) << 3)];         \
            bf16x8 fa1 = *(const bf16x8*)&L[am1 * 64 + ((ca ^ (am1 & 7)) << 3)];         \
            bf16x8 fb0 = *(const bf16x8*)&L[4096 + bn0 * 64 + ((ca ^ (bn0 & 7)) << 3)];  \
            bf16x8 fb1 = *(const bf16x8*)&L[4096 + bn1 * 64 + ((ca ^ (bn1 & 7)) << 3)];  \
            acc00 = __builtin_amdgcn_mfma_f32_16x16x32_bf16(fa0, fb0, acc00, 0, 0, 0);   \
            acc01 = __builtin_amdgcn_mfma_f32_16x16x32_bf16(fa0, fb1, acc01, 0, 0, 0);   \
            acc10 = __builtin_amdgcn_mfma_f32_16x16x32_bf16(fa1, fb0, acc10, 0, 0, 0);   \
            acc11 = __builtin_amdgcn_mfma_f32_16x16x32_bf16(fa1, fb1, acc11, 0, 0, 0);   \
        }                                                                                \
        __builtin_amdgcn_s_setprio(0);                                                   \
    } while (0)

    // Pipeline: loads issued 2 tiles ahead of consumption.
    LD(0, SA); COMMIT(SA, 0);
    LD(1, SB);
    __syncthreads();

    int p = 0;
    for (int tt = 0; tt < 36; tt += 2) {
        if (tt + 2 < 36) LD(tt + 2, SA);
        COMPUTE(p);
        COMMIT(SB, 1 - p);
        __syncthreads();
        p ^= 1;
        if (tt + 3 < 36) LD(tt + 3, SB);
        COMPUTE(p);
        if (tt + 2 < 36) {
            COMMIT(SA, 1 - p);
            __syncthreads();
            p ^= 1;
        }
    }
    __syncthreads();

#undef LD
#undef COMMIT
#undef COMPUTE

    // --- epilogue: z-tile via LDS (spans both buffers), LSTM cell update ---
    float* zt = (float*)&lds[0][0];         // [64 n_gathered][68 m] = 17.4 KB
    {
        const int rm = (lane >> 4) * 4;
        const int cn = lane & 15;
        *(float4*)&zt[(wn + cn) * 68 + wm + rm]           = *(float4*)&acc00;
        *(float4*)&zt[(wn + 16 + cn) * 68 + wm + rm]      = *(float4*)&acc01;
        *(float4*)&zt[(wn + cn) * 68 + wm + 16 + rm]      = *(float4*)&acc10;
        *(float4*)&zt[(wn + 16 + cn) * 68 + wm + 16 + rm] = *(float4*)&acc11;
    }
    __syncthreads();

    #pragma unroll
    for (int i2 = 0; i2 < 4; ++i2) {        // 1024 cell elems, 4/thread
        int e  = i2 * 256 + tid;
        int m  = e & 63;
        int jh = e >> 6;                    // hid slice 0..15
        float g4[4];
        #pragma unroll
        for (int gi = 0; gi < 4; ++gi)
            g4[gi] = zt[(gi * 16 + jh) * 68 + m] + bsel[gi * 128 + hid0 + jh];
        long idx = ((long)b * HW + hwl + m) * 128 + hid0 + jh;
        float si = 1.f / (1.f + expf(-g4[0]));
        float sf = 1.f / (1.f + expf(-g4[1]));
        float so = 1.f / (1.f + expf(-g4[3]));
        float cs = sf * csel[idx] + si * tanhf(g4[2]);
        float hs = so * tanhf(cs);
        csel[idx] = cs;
        ohh[idx] = f2bf(hs);
    }
}

// ---------------------------------------------------------------------------
// Mean pool over HW: seq2 hi plane [s][b][hw][hid] -> pooled
// ---------------------------------------------------------------------------
__global__ void pool_kernel(const unsigned short* __restrict__ s2h,
                            float* __restrict__ pooled) {
    int bs = blockIdx.x;            // s*BB + b
    int j  = threadIdx.x;           // 0..127
    const unsigned short* ph = s2h + (long)bs * HW * 128 + j;
    float sum = 0.f;
    #pragma unroll 8
    for (int hw = 0; hw < HW; ++hw)
        sum += bf2f(ph[hw * 128]);
    pooled[bs * HID + j] = sum * (1.f / HW);
}

// ---------------------------------------------------------------------------
// FC + ReLU + two scalar heads.
// ---------------------------------------------------------------------------
__global__ void head_kernel(const float* __restrict__ pooled,
                            const float* __restrict__ fc_w, const float* __restrict__ fc_b,
                            const float* __restrict__ fco_w, const float* __restrict__ fco_b,
                            const float* __restrict__ fca_w, const float* __restrict__ fca_b,
                            float* __restrict__ out) {
    int bs = blockIdx.x;          // b*S + s
    int b  = bs / SS;
    int s  = bs % SS;
    int j  = threadIdx.x;
    const float* prow = pooled + (long)(s * BB + b) * HID;
    float acc = fc_b[j];
    #pragma unroll 4
    for (int k = 0; k < HID; ++k) acc += fc_w[j * HID + k] * prow[k];
    float f = fmaxf(acc, 0.f);
    __shared__ float ro[128], ra[128];
    ro[j] = f * fco_w[j];
    ra[j] = f * fca_w[j];
    __syncthreads();
    for (int off = 64; off; off >>= 1) {
        if (j < off) { ro[j] += ro[j + off]; ra[j] += ra[j + off]; }
        __syncthreads();
    }
    if (j == 0) {
        out[bs]           = ro[0] + fco_b[0];
        out[BB * SS + bs] = ra[0] + fca_b[0];
    }
}

// ---------------------------------------------------------------------------
extern "C" void kernel_launch(void* const* d_in, const int* in_sizes, int n_in,
                              void* d_out, int out_size, void* d_ws, size_t ws_size,
                              hipStream_t stream) {
    const float* x      = (const float*)d_in[0];
    const float* conv_w = (const float*)d_in[1];
    const float* conv_b = (const float*)d_in[2];
    const float* init_h = (const float*)d_in[3];
    const float* init_c = (const float*)d_in[4];
    const float* fc_w   = (const float*)d_in[5];
    const float* fc_b   = (const float*)d_in[6];
    const float* fco_w  = (const float*)d_in[7];
    const float* fco_b  = (const float*)d_in[8];
    const float* fca_w  = (const float*)d_in[9];
    const float* fca_b  = (const float*)d_in[10];
    float* out = (float*)d_out;

    // Workspace carve-up — total ~60 MB.
    unsigned short* wh  = (unsigned short*)d_ws;            // 2,359,296
    unsigned short* xph = wh  + (long)DEPTH * COUT * KFULL; // SS*ACT = 8,388,608
    unsigned short* s1h = xph + (long)SS * ACT;
    unsigned short* s2h = s1h + (long)SS * ACT;
    unsigned short* h1h = s2h + (long)SS * ACT;             // ACT each
    unsigned short* h2h = h1h + ACT;
    float* c1     = (float*)(h2h + ACT);                    // ACT f32
    float* c2     = c1 + ACT;
    float* pooled = c2 + ACT;                               // 16,384
    unsigned short* zp = (unsigned short*)(pooled + SS * BB * HID); // 256 B zeros

    transpose_w_kernel<<<(DEPTH * K9 * COUT + 255) / 256, 256, 0, stream>>>(conv_w, wh);
    pack_x_kernel<<<dim3(SS * BB, HW / 64), 256, 0, stream>>>(x, (unsigned*)xph);
    init_state_kernel<<<ACT / 256, 256, 0, stream>>>(init_h, init_c, h1h, c1, 0);
    init_state_kernel<<<ACT / 256, 256, 0, stream>>>(init_h, init_c, h2h, c2, 1);
    zero_kernel<<<1, 64, 0, stream>>>((unsigned*)zp);

    for (int t = 0; t <= SS; ++t) {
        int do1 = (t < SS) ? 1 : 0;
        int do2 = (t >= 1) ? 1 : 0;
        int t1 = (t < SS) ? t : SS - 1;          // clamped for safe ptr arith
        int u2 = (t >= 1) ? t - 1 : 0;
        const unsigned short* ax1h = xph + (long)t1 * ACT;
        const unsigned short* ah1h = (t1 == 0) ? h1h : s1h + (long)(t1 - 1) * ACT;
        unsigned short* ao1h = s1h + (long)t1 * ACT;
        const unsigned short* ax2h = s1h + (long)u2 * ACT;
        const unsigned short* ah2h = (u2 == 0) ? h2h : s2h + (long)(u2 - 1) * ACT;
        unsigned short* ao2h = s2h + (long)u2 * ACT;
        step_dual<<<512, 256, 0, stream>>>(
            ax1h, ah1h, c1, ao1h,
            ax2h, ah2h, c2, ao2h,
            wh, conv_b, zp, do1, do2);
    }

    pool_kernel<<<SS * BB, 128, 0, stream>>>(s2h, pooled);
    head_kernel<<<BB * SS, 128, 0, stream>>>(pooled, fc_w, fc_b, fco_w, fco_b, fca_w, fca_b, out);
}

// Round 20
// 862.874 us; speedup vs baseline: 3.2075x; 1.0627x over previous
//
#include <hip/hip_runtime.h>

// Problem constants
#define BB 4
#define SS 32
#define CC 128
#define HH 16
#define WW 32
#define HID 128
#define DEPTH 2
#define CIN 256           // CC + HID
#define COUT 512          // 4*HID
#define K9 (CIN * 9)      // 2304
#define KH 1152           // per-source K: tap-major k = tap*128 + ch
#define KFULL (2 * KH)    // 2304 = x-part rows then h-part rows
#define HW (HH * WW)      // 512
#define MM (BB * HW)      // 2048
#define ACT (BB * HW * 128) // 262144 = one activation slice (b,hw,ch)

typedef __attribute__((ext_vector_type(4))) float f32x4;
typedef __attribute__((ext_vector_type(8))) short bf16x8;

static __device__ __forceinline__ unsigned short f2bf(float f) {
    union { float f; unsigned u; } v; v.f = f;
    unsigned r = v.u + 0x7FFF + ((v.u >> 16) & 1);   // RNE
    return (unsigned short)(r >> 16);
}
static __device__ __forceinline__ float bf2f(unsigned short h) {
    union { float f; unsigned u; } v; v.u = ((unsigned)h) << 16; return v.f;
}

// ---------------------------------------------------------------------------
// Weight transpose -> single bf16 plane (RNE), k-major:
//   wh [DEPTH][COUT_g][KFULL] ushort
// k row: cin<CC -> tap*CC+cin (x block) else KH + tap*HID + (cin-CC) (h block)
// n gate-gathered: n' = (r>>4)*64 + g*16 + (r&15)
// ---------------------------------------------------------------------------
__global__ void transpose_w_kernel(const float* __restrict__ w,
                                   unsigned short* __restrict__ wh) {
    int idx = blockIdx.x * 256 + threadIdx.x;
    if (idx >= DEPTH * K9 * COUT) return;
    int n = idx % COUT;
    int k = (idx / COUT) % K9;
    int d = idx / (COUT * K9);
    int cin = k / 9, tap = k % 9;
    float v = w[(((long)(d * COUT + n) * CIN + cin) * 9) + tap];
    int row = (cin < CC) ? (tap * CC + cin) : (KH + tap * HID + (cin - CC));
    int g = n >> 7, r = n & 127;
    int ng = (r >> 4) * 64 + g * 16 + (r & 15);
    wh[((long)d * COUT + ng) * KFULL + row] = f2bf(v);
}

// ---------------------------------------------------------------------------
// Pack x [B][S][CC][HW] fp32 -> bf16 plane [s][b][hw][cc] via LDS transpose.
// grid (SS*BB, HW/64), 256 threads.
// ---------------------------------------------------------------------------
__global__ void pack_x_kernel(const float* __restrict__ x,
                              unsigned* __restrict__ xh32) {
    __shared__ unsigned lh[128 * 33];    // [cc][hw-pair], pad 33
    const int tid = threadIdx.x;
    const int sb  = blockIdx.x;          // s*BB + b
    const int s   = sb >> 2;
    const int b   = sb & 3;
    const int hw0 = blockIdx.y * 64;
    const float* src = x + ((long)(b * SS + s) * CC) * HW;

    #pragma unroll
    for (int it = 0; it < 16; ++it) {
        int cc = it * 8 + (tid >> 5);
        int hw = (tid & 31) * 2;
        float2 v = *(const float2*)&src[cc * HW + hw0 + hw];
        unsigned short h0 = f2bf(v.x), h1 = f2bf(v.y);
        lh[cc * 33 + (hw >> 1)] = (unsigned)h0 | ((unsigned)h1 << 16);
    }
    __syncthreads();
    const unsigned short* lhs = (const unsigned short*)lh;
    #pragma unroll
    for (int it = 0; it < 16; ++it) {
        int hw = it * 4 + (tid >> 6);
        int c2 = tid & 63;               // cc pair
        unsigned short a0 = lhs[(2 * c2) * 66 + hw];
        unsigned short a1 = lhs[(2 * c2 + 1) * 66 + hw];
        long o = ((long)sb * HW + hw0 + hw) * 64 + c2;
        xh32[o] = (unsigned)a0 | ((unsigned)a1 << 16);
    }
}

// ---------------------------------------------------------------------------
// Broadcast init_h/init_c[d] into bf16 h plane ([b][hw][hid]) + fp32 c
// ---------------------------------------------------------------------------
__global__ void init_state_kernel(const float* __restrict__ ih, const float* __restrict__ ic,
                                  unsigned short* __restrict__ hh,
                                  float* __restrict__ c, int d) {
    int idx = blockIdx.x * 256 + threadIdx.x;   // ACT = 262144
    int hid = idx & 127;
    hh[idx] = f2bf(ih[d * HID + hid]);
    c[idx] = ic[d * HID + hid];
}

// Zero the 256B OOB page (workspace is poisoned 0xAA before timing)
__global__ void zero_kernel(unsigned* __restrict__ zp) { zp[threadIdx.x] = 0u; }

// ---------------------------------------------------------------------------
// DUAL-LAYER fused step kernel — bf16 A and B, global_load_lds staging:
//  - staging = 4 async global_load_lds(16B) per thread per tile; destination
//    is wave-uniform base + lane*16 (matches our row/chunk geometry exactly);
//    XOR swizzle applied on the per-lane SOURCE address (LDS stays linear).
//  - next tile's loads issued BEFORE compute; the vmcnt(0) drain at the
//    barrier guarantees arrival. No register staging, no ds_writes.
// Per wave-sub: 4 LDS reads -> 4 MFMAs. LDS 32 KB/wg (2 x 16 KB buffers).
// M=64, N=64 per wg, 256 thr = 4 waves (2m x 2n of 32x32 from 16x16 frags).
// Grid 512 flat, XCD-stable swizzle. K = 36 tiles (18 x-part + 18 h-part).
// ---------------------------------------------------------------------------
__launch_bounds__(256)
__global__ void step_dual(
    const unsigned short* __restrict__ x1h, const unsigned short* __restrict__ h1h,
    float* __restrict__ c1, unsigned short* __restrict__ o1h,
    const unsigned short* __restrict__ x2h, const unsigned short* __restrict__ h2h,
    float* __restrict__ c2, unsigned short* __restrict__ o2h,
    const unsigned short* __restrict__ wh,
    const float* __restrict__ bias, const unsigned short* __restrict__ zp,
    int do1, int do2)
{
    // buf layout (ushort idx): A [0,4096) rows m*64+k, B [4096,8192).
    // 2 bufs = 32 KB.
    __shared__ __align__(16) unsigned short lds[2][8192];

    const int bid  = blockIdx.x;
    const int xcd  = bid & 7;
    const int q    = bid >> 3;               // 0..63
    const int mblk = q & 31;
    const int pp   = xcd + ((q >> 5) << 3);  // panel 0..15
    const int nblk = pp & 7;
    const int z    = pp >> 3;
    if (z == 0) { if (!do1) return; } else { if (!do2) return; }

    const unsigned short* axh = z ? x2h : x1h;
    const unsigned short* ahh = z ? h2h : h1h;
    const unsigned short* wph = wh + (long)z * COUT * KFULL;
    const float* bsel  = bias + z * COUT;
    float* csel        = z ? c2 : c1;
    unsigned short* ohh = z ? o2h : o1h;

    const int m0   = mblk * 64;
    const int n0g  = nblk * 64;
    const int hid0 = nblk * 16;
    const int tid  = threadIdx.x;
    const int lane = tid & 63;
    const int wv   = tid >> 6;              // wave 0..3
    const int wm   = (wv >> 1) * 32;        // wave m offset (32x32 tile)
    const int wn   = (wv & 1) * 32;         // wave n offset
    const int b    = m0 >> 9;
    const int hwl  = m0 & 511;
    const int y0   = hwl >> 5;              // first image row (2 rows per wg)

    // staging geometry: wave wv stages rows 16wv..16wv+15 of each plane.
    // lane: row1 = 16wv + (lane>>3), row2 = row1+8, chunk j = lane&7.
    // Source chunk = j^(row&7) (XOR swizzle); LDS write is HW-automatic
    // (base + lane*16 == row-major linear slot) -> conflict-free.
    const int row1 = wv * 16 + (lane >> 3);
    const int row2 = row1 + 8;
    const int jch  = lane & 7;
    const int jx1  = jch ^ (row1 & 7);
    const int jx2  = jch ^ (row2 & 7);
    const int sx1  = row1 & 31, sy1b = row1 >> 5;
    const int sx2  = row2 & 31, sy2b = row2 >> 5;
    const long bhw = (long)b * HW;
    const long bro1 = (long)(n0g + row1) * KFULL + jx1 * 8;  // B row bases
    const long bro2 = (long)(n0g + row2) * KFULL + jx2 * 8;

#define ISSUE(tt, pb) do {                                                        \
        const int _tt = (tt);                                                     \
        const long _k0 = (long)_tt * 64;                                          \
        int _ks = (_tt < 18) ? _tt : _tt - 18;                                    \
        int _tap = _ks >> 1;                                                      \
        int _c0  = (_ks & 1) << 6;                                                \
        int _ky  = _tap / 3 - 1;                                                  \
        int _kx  = _tap - (_tap / 3) * 3 - 1;                                     \
        const unsigned short* _sh = (_tt < 18) ? axh : ahh;                       \
        int _y1 = y0 + sy1b + _ky, _x1 = sx1 + _kx;                               \
        int _y2 = y0 + sy2b + _ky, _x2 = sx2 + _kx;                               \
        bool _o1 = (unsigned)_y1 < (unsigned)HH && (unsigned)_x1 < (unsigned)WW;  \
        bool _o2 = (unsigned)_y2 < (unsigned)HH && (unsigned)_x2 < (unsigned)WW;  \
        long _a1 = ((bhw + _y1 * WW + _x1) << 7) + _c0 + jx1 * 8;                 \
        long _a2 = ((bhw + _y2 * WW + _x2) << 7) + _c0 + jx2 * 8;                 \
        __builtin_amdgcn_global_load_lds(                                         \
            (const unsigned int*)(_o1 ? _sh + _a1 : zp),                          \
            (unsigned int*)&lds[pb][wv * 1024], 16, 0, 0);                        \
        __builtin_amdgcn_global_load_lds(                                         \
            (const unsigned int*)(_o2 ? _sh + _a2 : zp),                          \
            (unsigned int*)&lds[pb][wv * 1024 + 512], 16, 0, 0);                  \
        __builtin_amdgcn_global_load_lds(                                         \
            (const unsigned int*)(wph + bro1 + _k0),                              \
            (unsigned int*)&lds[pb][4096 + wv * 1024], 16, 0, 0);                 \
        __builtin_amdgcn_global_load_lds(                                         \
            (const unsigned int*)(wph + bro2 + _k0),                              \
            (unsigned int*)&lds[pb][4096 + wv * 1024 + 512], 16, 0, 0);           \
    } while (0)

    f32x4 acc00 = (f32x4){0.f,0.f,0.f,0.f};
    f32x4 acc01 = (f32x4){0.f,0.f,0.f,0.f};
    f32x4 acc10 = (f32x4){0.f,0.f,0.f,0.f};
    f32x4 acc11 = (f32x4){0.f,0.f,0.f,0.f};

    const int fr  = lane & 15;
    const int kqi = lane >> 4;              // 0..3 (k chunk within sub)
    const int am0 = wm + fr;                // A rows (2 m-frags)
    const int am1 = wm + 16 + fr;
    const int bn0 = wn + fr;                // B rows (2 n-frags)
    const int bn1 = wn + 16 + fr;

#define COMPUTE(P) do {                                                                  \
        const unsigned short* L = &lds[P][0];                                            \
        __builtin_amdgcn_s_setprio(1);                                                   \
        _Pragma("unroll")                                                                \
        for (int s = 0; s < 2; ++s) {                                                    \
            const int ca = s * 4 + kqi;     /* chunk 0..7 */                             \
            bf16x8 fa0 = *(const bf16x8*)&L[am0 * 64 + ((ca ^ (am0 & 7)) << 3)];         \
            bf16x8 fa1 = *(const bf16x8*)&L[am1 * 64 + ((ca ^ (am1 & 7)) << 3)];         \
            bf16x8 fb0 = *(const bf16x8*)&L[4096 + bn0 * 64 + ((ca ^ (bn0 & 7)) << 3)];  \
            bf16x8 fb1 = *(const bf16x8*)&L[4096 + bn1 * 64 + ((ca ^ (bn1 & 7)) << 3)];  \
            acc00 = __builtin_amdgcn_mfma_f32_16x16x32_bf16(fa0, fb0, acc00, 0, 0, 0);   \
            acc01 = __builtin_amdgcn_mfma_f32_16x16x32_bf16(fa0, fb1, acc01, 0, 0, 0);   \
            acc10 = __builtin_amdgcn_mfma_f32_16x16x32_bf16(fa1, fb0, acc10, 0, 0, 0);   \
            acc11 = __builtin_amdgcn_mfma_f32_16x16x32_bf16(fa1, fb1, acc11, 0, 0, 0);   \
        }                                                                                \
        __builtin_amdgcn_s_setprio(0);                                                   \
    } while (0)

    // Pipeline: issue tile tt+1 into the other buffer, compute tile tt, then
    // barrier (compiler drains vmcnt(0) before s_barrier -> loads landed).
    ISSUE(0, 0);
    __syncthreads();

    int p = 0;
    for (int tt = 0; tt < 36; ++tt) {
        if (tt + 1 < 36) ISSUE(tt + 1, 1 - p);
        COMPUTE(p);
        __syncthreads();
        p ^= 1;
    }

#undef ISSUE
#undef COMPUTE

    // --- epilogue: z-tile via LDS (spans both buffers), LSTM cell update ---
    float* zt = (float*)&lds[0][0];         // [64 n_gathered][68 m] = 17.4 KB
    {
        const int rm = (lane >> 4) * 4;
        const int cn = lane & 15;
        *(float4*)&zt[(wn + cn) * 68 + wm + rm]           = *(float4*)&acc00;
        *(float4*)&zt[(wn + 16 + cn) * 68 + wm + rm]      = *(float4*)&acc01;
        *(float4*)&zt[(wn + cn) * 68 + wm + 16 + rm]      = *(float4*)&acc10;
        *(float4*)&zt[(wn + 16 + cn) * 68 + wm + 16 + rm] = *(float4*)&acc11;
    }
    __syncthreads();

    #pragma unroll
    for (int i2 = 0; i2 < 4; ++i2) {        // 1024 cell elems, 4/thread
        int e  = i2 * 256 + tid;
        int m  = e & 63;
        int jh = e >> 6;                    // hid slice 0..15
        float g4[4];
        #pragma unroll
        for (int gi = 0; gi < 4; ++gi)
            g4[gi] = zt[(gi * 16 + jh) * 68 + m] + bsel[gi * 128 + hid0 + jh];
        long idx = ((long)b * HW + hwl + m) * 128 + hid0 + jh;
        float si = 1.f / (1.f + expf(-g4[0]));
        float sf = 1.f / (1.f + expf(-g4[1]));
        float so = 1.f / (1.f + expf(-g4[3]));
        float cs = sf * csel[idx] + si * tanhf(g4[2]);
        float hs = so * tanhf(cs);
        csel[idx] = cs;
        ohh[idx] = f2bf(hs);
    }
}

// ---------------------------------------------------------------------------
// Mean pool over HW: seq2 plane [s][b][hw][hid] -> pooled
// ---------------------------------------------------------------------------
__global__ void pool_kernel(const unsigned short* __restrict__ s2h,
                            float* __restrict__ pooled) {
    int bs = blockIdx.x;            // s*BB + b
    int j  = threadIdx.x;           // 0..127
    const unsigned short* ph = s2h + (long)bs * HW * 128 + j;
    float sum = 0.f;
    #pragma unroll 8
    for (int hw = 0; hw < HW; ++hw)
        sum += bf2f(ph[hw * 128]);
    pooled[bs * HID + j] = sum * (1.f / HW);
}

// ---------------------------------------------------------------------------
// FC + ReLU + two scalar heads.
// ---------------------------------------------------------------------------
__global__ void head_kernel(const float* __restrict__ pooled,
                            const float* __restrict__ fc_w, const float* __restrict__ fc_b,
                            const float* __restrict__ fco_w, const float* __restrict__ fco_b,
                            const float* __restrict__ fca_w, const float* __restrict__ fca_b,
                            float* __restrict__ out) {
    int bs = blockIdx.x;          // b*S + s
    int b  = bs / SS;
    int s  = bs % SS;
    int j  = threadIdx.x;
    const float* prow = pooled + (long)(s * BB + b) * HID;
    float acc = fc_b[j];
    #pragma unroll 4
    for (int k = 0; k < HID; ++k) acc += fc_w[j * HID + k] * prow[k];
    float f = fmaxf(acc, 0.f);
    __shared__ float ro[128], ra[128];
    ro[j] = f * fco_w[j];
    ra[j] = f * fca_w[j];
    __syncthreads();
    for (int off = 64; off; off >>= 1) {
        if (j < off) { ro[j] += ro[j + off]; ra[j] += ra[j + off]; }
        __syncthreads();
    }
    if (j == 0) {
        out[bs]           = ro[0] + fco_b[0];
        out[BB * SS + bs] = ra[0] + fca_b[0];
    }
}

// ---------------------------------------------------------------------------
extern "C" void kernel_launch(void* const* d_in, const int* in_sizes, int n_in,
                              void* d_out, int out_size, void* d_ws, size_t ws_size,
                              hipStream_t stream) {
    const float* x      = (const float*)d_in[0];
    const float* conv_w = (const float*)d_in[1];
    const float* conv_b = (const float*)d_in[2];
    const float* init_h = (const float*)d_in[3];
    const float* init_c = (const float*)d_in[4];
    const float* fc_w   = (const float*)d_in[5];
    const float* fc_b   = (const float*)d_in[6];
    const float* fco_w  = (const float*)d_in[7];
    const float* fco_b  = (const float*)d_in[8];
    const float* fca_w  = (const float*)d_in[9];
    const float* fca_b  = (const float*)d_in[10];
    float* out = (float*)d_out;

    // Workspace carve-up — total ~60 MB.
    unsigned short* wh  = (unsigned short*)d_ws;            // 2,359,296
    unsigned short* xph = wh  + (long)DEPTH * COUT * KFULL; // SS*ACT = 8,388,608
    unsigned short* s1h = xph + (long)SS * ACT;
    unsigned short* s2h = s1h + (long)SS * ACT;
    unsigned short* h1h = s2h + (long)SS * ACT;             // ACT each
    unsigned short* h2h = h1h + ACT;
    float* c1     = (float*)(h2h + ACT);                    // ACT f32
    float* c2     = c1 + ACT;
    float* pooled = c2 + ACT;                               // 16,384
    unsigned short* zp = (unsigned short*)(pooled + SS * BB * HID); // 256 B zeros

    transpose_w_kernel<<<(DEPTH * K9 * COUT + 255) / 256, 256, 0, stream>>>(conv_w, wh);
    pack_x_kernel<<<dim3(SS * BB, HW / 64), 256, 0, stream>>>(x, (unsigned*)xph);
    init_state_kernel<<<ACT / 256, 256, 0, stream>>>(init_h, init_c, h1h, c1, 0);
    init_state_kernel<<<ACT / 256, 256, 0, stream>>>(init_h, init_c, h2h, c2, 1);
    zero_kernel<<<1, 64, 0, stream>>>((unsigned*)zp);

    for (int t = 0; t <= SS; ++t) {
        int do1 = (t < SS) ? 1 : 0;
        int do2 = (t >= 1) ? 1 : 0;
        int t1 = (t < SS) ? t : SS - 1;          // clamped for safe ptr arith
        int u2 = (t >= 1) ? t - 1 : 0;
        const unsigned short* ax1h = xph + (long)t1 * ACT;
        const unsigned short* ah1h = (t1 == 0) ? h1h : s1h + (long)(t1 - 1) * ACT;
        unsigned short* ao1h = s1h + (long)t1 * ACT;
        const unsigned short* ax2h = s1h + (long)u2 * ACT;
        const unsigned short* ah2h = (u2 == 0) ? h2h : s2h + (long)(u2 - 1) * ACT;
        unsigned short* ao2h = s2h + (long)u2 * ACT;
        step_dual<<<512, 256, 0, stream>>>(
            ax1h, ah1h, c1, ao1h,
            ax2h, ah2h, c2, ao2h,
            wh, conv_b, zp, do1, do2);
    }

    pool_kernel<<<SS * BB, 128, 0, stream>>>(s2h, pooled);
    head_kernel<<<BB * SS, 128, 0, stream>>>(pooled, fc_w, fc_b, fco_w, fco_b, fca_w, fca_b, out);
}

// Round 21
// 698.650 us; speedup vs baseline: 3.9614x; 1.2351x over previous
//
#include <hip/hip_runtime.h>

// Problem constants
#define BB 4
#define SS 32
#define CC 128
#define HH 16
#define WW 32
#define HID 128
#define DEPTH 2
#define CIN 256           // CC + HID
#define COUT 512          // 4*HID
#define K9 (CIN * 9)      // 2304
#define KH 1152           // per-source K: tap-major k = tap*128 + ch
#define KFULL (2 * KH)    // 2304 = x-part rows then h-part rows
#define HW (HH * WW)      // 512
#define MM (BB * HW)      // 2048
#define ACT (BB * HW * 128) // 262144 = one activation slice (b,hw,ch)

typedef __attribute__((ext_vector_type(4))) float f32x4;
typedef __attribute__((ext_vector_type(8))) short bf16x8;

static __device__ __forceinline__ unsigned short f2bf(float f) {
    union { float f; unsigned u; } v; v.f = f;
    unsigned r = v.u + 0x7FFF + ((v.u >> 16) & 1);   // RNE
    return (unsigned short)(r >> 16);
}
static __device__ __forceinline__ float bf2f(unsigned short h) {
    union { float f; unsigned u; } v; v.u = ((unsigned)h) << 16; return v.f;
}

// ---------------------------------------------------------------------------
// Weight transpose -> single bf16 plane (RNE), k-major:
//   wh [DEPTH][COUT_g][KFULL] ushort
// k row: cin<CC -> tap*CC+cin (x block) else KH + tap*HID + (cin-CC) (h block)
// n gate-gathered: n' = (r>>4)*64 + g*16 + (r&15)
// ---------------------------------------------------------------------------
__global__ void transpose_w_kernel(const float* __restrict__ w,
                                   unsigned short* __restrict__ wh) {
    int idx = blockIdx.x * 256 + threadIdx.x;
    if (idx >= DEPTH * K9 * COUT) return;
    int n = idx % COUT;
    int k = (idx / COUT) % K9;
    int d = idx / (COUT * K9);
    int cin = k / 9, tap = k % 9;
    float v = w[(((long)(d * COUT + n) * CIN + cin) * 9) + tap];
    int row = (cin < CC) ? (tap * CC + cin) : (KH + tap * HID + (cin - CC));
    int g = n >> 7, r = n & 127;
    int ng = (r >> 4) * 64 + g * 16 + (r & 15);
    wh[((long)d * COUT + ng) * KFULL + row] = f2bf(v);
}

// ---------------------------------------------------------------------------
// Pack x [B][S][CC][HW] fp32 -> bf16 plane [s][b][hw][cc] via LDS transpose.
// grid (SS*BB, HW/64), 256 threads.
// ---------------------------------------------------------------------------
__global__ void pack_x_kernel(const float* __restrict__ x,
                              unsigned* __restrict__ xh32) {
    __shared__ unsigned lh[128 * 33];    // [cc][hw-pair], pad 33
    const int tid = threadIdx.x;
    const int sb  = blockIdx.x;          // s*BB + b
    const int s   = sb >> 2;
    const int b   = sb & 3;
    const int hw0 = blockIdx.y * 64;
    const float* src = x + ((long)(b * SS + s) * CC) * HW;

    #pragma unroll
    for (int it = 0; it < 16; ++it) {
        int cc = it * 8 + (tid >> 5);
        int hw = (tid & 31) * 2;
        float2 v = *(const float2*)&src[cc * HW + hw0 + hw];
        unsigned short h0 = f2bf(v.x), h1 = f2bf(v.y);
        lh[cc * 33 + (hw >> 1)] = (unsigned)h0 | ((unsigned)h1 << 16);
    }
    __syncthreads();
    const unsigned short* lhs = (const unsigned short*)lh;
    #pragma unroll
    for (int it = 0; it < 16; ++it) {
        int hw = it * 4 + (tid >> 6);
        int c2 = tid & 63;               // cc pair
        unsigned short a0 = lhs[(2 * c2) * 66 + hw];
        unsigned short a1 = lhs[(2 * c2 + 1) * 66 + hw];
        long o = ((long)sb * HW + hw0 + hw) * 64 + c2;
        xh32[o] = (unsigned)a0 | ((unsigned)a1 << 16);
    }
}

// ---------------------------------------------------------------------------
// Broadcast init_h/init_c[d] into bf16 h plane ([b][hw][hid]) + fp32 c
// ---------------------------------------------------------------------------
__global__ void init_state_kernel(const float* __restrict__ ih, const float* __restrict__ ic,
                                  unsigned short* __restrict__ hh,
                                  float* __restrict__ c, int d) {
    int idx = blockIdx.x * 256 + threadIdx.x;   // ACT = 262144
    int hid = idx & 127;
    hh[idx] = f2bf(ih[d * HID + hid]);
    c[idx] = ic[d * HID + hid];
}

// Zero the 256B OOB page (workspace is poisoned 0xAA before timing)
__global__ void zero_kernel(unsigned* __restrict__ zp) { zp[threadIdx.x] = 0u; }

// ---------------------------------------------------------------------------
// DUAL-LAYER fused step kernel — bf16 A/B, global_load_lds staging, BK=128
// (one full conv tap per phase -> 18 phases, half the barriers of BK=64).
//  - staging = 8 async global_load_lds(16B)/thread/phase; destination is
//    wave-uniform base + lane*16; XOR swizzle on the per-lane SOURCE address.
//  - next phase's loads issued BEFORE compute; vmcnt(0) drain at the barrier
//    guarantees arrival after a full double-length compute phase.
//  - vectorized epilogue: float4 c RMW + packed 8B h store per thread.
// Per wave per phase: 16 LDS reads -> 16 MFMAs. LDS 64 KB/wg (2 x 32 KB).
// M=64, N=64 per wg, 256 thr = 4 waves (2m x 2n of 32x32 from 16x16 frags).
// Grid 512 flat, XCD-stable swizzle. K = 18 phases (9 x-part + 9 h-part).
// ---------------------------------------------------------------------------
__launch_bounds__(256)
__global__ void step_dual(
    const unsigned short* __restrict__ x1h, const unsigned short* __restrict__ h1h,
    float* __restrict__ c1, unsigned short* __restrict__ o1h,
    const unsigned short* __restrict__ x2h, const unsigned short* __restrict__ h2h,
    float* __restrict__ c2, unsigned short* __restrict__ o2h,
    const unsigned short* __restrict__ wh,
    const float* __restrict__ bias, const unsigned short* __restrict__ zp,
    int do1, int do2)
{
    // buf layout (ushort idx): A [0,8192) rows m*128+k, B [8192,16384).
    // 2 bufs = 64 KB.
    __shared__ __align__(16) unsigned short lds[2][16384];

    const int bid  = blockIdx.x;
    const int xcd  = bid & 7;
    const int q    = bid >> 3;               // 0..63
    const int mblk = q & 31;
    const int pp   = xcd + ((q >> 5) << 3);  // panel 0..15
    const int nblk = pp & 7;
    const int z    = pp >> 3;
    if (z == 0) { if (!do1) return; } else { if (!do2) return; }

    const unsigned short* axh = z ? x2h : x1h;
    const unsigned short* ahh = z ? h2h : h1h;
    const unsigned short* wph = wh + (long)z * COUT * KFULL;
    const float* bsel  = bias + z * COUT;
    float* csel        = z ? c2 : c1;
    unsigned short* ohh = z ? o2h : o1h;

    const int m0   = mblk * 64;
    const int n0g  = nblk * 64;
    const int hid0 = nblk * 16;
    const int tid  = threadIdx.x;
    const int lane = tid & 63;
    const int wv   = tid >> 6;              // wave 0..3
    const int wm   = (wv >> 1) * 32;        // wave m offset (32x32 tile)
    const int wn   = (wv & 1) * 32;         // wave n offset
    const int b    = m0 >> 9;
    const int hwl  = m0 & 511;
    const int y0   = hwl >> 5;              // first image row (2 rows per wg)
    const long bhw = (long)b * HW;

    // Staging geometry (per plane): wave wv stages rows 16wv..16wv+15, each
    // row = 128 k (16 chunks of 8 ushorts). Instruction s (0..3): lane slot
    // row = wv*16 + s*4 + (lane>>4), chunk j = lane&15; source chunk
    // j^(row&7) (XOR swizzle); LDS dest = wave-uniform base + lane*16.
    int sy_[4], sx_[4], ax_[4];
    long bro_[4];
    #pragma unroll
    for (int s = 0; s < 4; ++s) {
        int row = wv * 16 + s * 4 + (lane >> 4);
        int jx  = (lane & 15) ^ (row & 7);
        sx_[s] = row & 31;
        sy_[s] = y0 + (row >> 5);
        ax_[s] = jx * 8;
        bro_[s] = (long)(n0g + row) * KFULL + jx * 8;
    }

#define ISSUE(tt, pb) do {                                                        \
        const int _tt = (tt);                                                     \
        const int _tap = (_tt < 9) ? _tt : _tt - 9;                               \
        const unsigned short* _sh = (_tt < 9) ? axh : ahh;                        \
        const int _ky = _tap / 3 - 1;                                             \
        const int _kx = _tap - (_tap / 3) * 3 - 1;                                \
        const long _bk = (long)_tt * 128;                                         \
        _Pragma("unroll")                                                         \
        for (int _s = 0; _s < 4; ++_s) {                                          \
            int _yy = sy_[_s] + _ky, _xq = sx_[_s] + _kx;                         \
            bool _ok = (unsigned)_yy < (unsigned)HH && (unsigned)_xq < (unsigned)WW;\
            long _a = ((bhw + _yy * WW + _xq) << 7) + ax_[_s];                    \
            __builtin_amdgcn_global_load_lds(                                     \
                (const unsigned int*)(_ok ? _sh + _a : zp),                       \
                (unsigned int*)&lds[pb][wv * 2048 + _s * 512], 16, 0, 0);         \
            __builtin_amdgcn_global_load_lds(                                     \
                (const unsigned int*)(wph + bro_[_s] + _bk),                      \
                (unsigned int*)&lds[pb][8192 + wv * 2048 + _s * 512], 16, 0, 0);  \
        }                                                                         \
    } while (0)

    f32x4 acc00 = (f32x4){0.f,0.f,0.f,0.f};
    f32x4 acc01 = (f32x4){0.f,0.f,0.f,0.f};
    f32x4 acc10 = (f32x4){0.f,0.f,0.f,0.f};
    f32x4 acc11 = (f32x4){0.f,0.f,0.f,0.f};

    const int fr  = lane & 15;
    const int kqi = lane >> 4;              // 0..3 (k chunk within sub)
    const int am0 = wm + fr;                // A rows (2 m-frags)
    const int am1 = wm + 16 + fr;
    const int bn0 = wn + fr;                // B rows (2 n-frags)
    const int bn1 = wn + 16 + fr;

#define COMPUTE(P) do {                                                                   \
        const unsigned short* L = &lds[P][0];                                             \
        __builtin_amdgcn_s_setprio(1);                                                    \
        _Pragma("unroll")                                                                 \
        for (int s2 = 0; s2 < 4; ++s2) {                                                  \
            const int ca = s2 * 4 + kqi;    /* chunk 0..15 */                             \
            bf16x8 fa0 = *(const bf16x8*)&L[am0 * 128 + ((ca ^ (am0 & 7)) << 3)];         \
            bf16x8 fa1 = *(const bf16x8*)&L[am1 * 128 + ((ca ^ (am1 & 7)) << 3)];         \
            bf16x8 fb0 = *(const bf16x8*)&L[8192 + bn0 * 128 + ((ca ^ (bn0 & 7)) << 3)];  \
            bf16x8 fb1 = *(const bf16x8*)&L[8192 + bn1 * 128 + ((ca ^ (bn1 & 7)) << 3)];  \
            acc00 = __builtin_amdgcn_mfma_f32_16x16x32_bf16(fa0, fb0, acc00, 0, 0, 0);    \
            acc01 = __builtin_amdgcn_mfma_f32_16x16x32_bf16(fa0, fb1, acc01, 0, 0, 0);    \
            acc10 = __builtin_amdgcn_mfma_f32_16x16x32_bf16(fa1, fb0, acc10, 0, 0, 0);    \
            acc11 = __builtin_amdgcn_mfma_f32_16x16x32_bf16(fa1, fb1, acc11, 0, 0, 0);    \
        }                                                                                 \
        __builtin_amdgcn_s_setprio(0);                                                    \
    } while (0)

    // Pipeline: issue phase tt+1 into the other buffer, compute phase tt,
    // then barrier (compiler drains vmcnt(0) before s_barrier).
    ISSUE(0, 0);
    __syncthreads();

    int p = 0;
    for (int tt = 0; tt < 18; ++tt) {
        if (tt + 1 < 18) ISSUE(tt + 1, 1 - p);
        COMPUTE(p);
        __syncthreads();
        p ^= 1;
    }

#undef ISSUE
#undef COMPUTE

    // --- epilogue: z-tile via LDS (fits in buffer 0), LSTM cell update ---
    float* zt = (float*)&lds[0][0];         // [64 n_gathered][68 m] = 17.4 KB
    {
        const int rm = (lane >> 4) * 4;
        const int cn = lane & 15;
        *(float4*)&zt[(wn + cn) * 68 + wm + rm]           = *(float4*)&acc00;
        *(float4*)&zt[(wn + 16 + cn) * 68 + wm + rm]      = *(float4*)&acc01;
        *(float4*)&zt[(wn + cn) * 68 + wm + 16 + rm]      = *(float4*)&acc10;
        *(float4*)&zt[(wn + 16 + cn) * 68 + wm + 16 + rm] = *(float4*)&acc11;
    }
    __syncthreads();

    // Each thread: one m, 4 consecutive hid -> float4 c RMW + 8B packed h.
    {
        const int m    = tid & 63;
        const int jset = tid >> 6;          // 0..3
        float g[4][4];
        #pragma unroll
        for (int ji = 0; ji < 4; ++ji) {
            int jh = jset * 4 + ji;
            #pragma unroll
            for (int gi = 0; gi < 4; ++gi)
                g[ji][gi] = zt[(gi * 16 + jh) * 68 + m] + bsel[gi * 128 + hid0 + jh];
        }
        long base = ((long)b * HW + hwl + m) * 128 + hid0 + jset * 4;
        f32x4 cv = *(const f32x4*)&csel[base];
        float hv[4];
        #pragma unroll
        for (int ji = 0; ji < 4; ++ji) {
            float si = 1.f / (1.f + expf(-g[ji][0]));
            float sf = 1.f / (1.f + expf(-g[ji][1]));
            float so = 1.f / (1.f + expf(-g[ji][3]));
            float cs = sf * cv[ji] + si * tanhf(g[ji][2]);
            cv[ji] = cs;
            hv[ji] = so * tanhf(cs);
        }
        *(f32x4*)&csel[base] = cv;
        uint2 hp;
        hp.x = (unsigned)f2bf(hv[0]) | ((unsigned)f2bf(hv[1]) << 16);
        hp.y = (unsigned)f2bf(hv[2]) | ((unsigned)f2bf(hv[3]) << 16);
        *(uint2*)&ohh[base] = hp;
    }
}

// ---------------------------------------------------------------------------
// Mean pool over HW: seq2 plane [s][b][hw][hid] -> pooled
// ---------------------------------------------------------------------------
__global__ void pool_kernel(const unsigned short* __restrict__ s2h,
                            float* __restrict__ pooled) {
    int bs = blockIdx.x;            // s*BB + b
    int j  = threadIdx.x;           // 0..127
    const unsigned short* ph = s2h + (long)bs * HW * 128 + j;
    float sum = 0.f;
    #pragma unroll 8
    for (int hw = 0; hw < HW; ++hw)
        sum += bf2f(ph[hw * 128]);
    pooled[bs * HID + j] = sum * (1.f / HW);
}

// ---------------------------------------------------------------------------
// FC + ReLU + two scalar heads.
// ---------------------------------------------------------------------------
__global__ void head_kernel(const float* __restrict__ pooled,
                            const float* __restrict__ fc_w, const float* __restrict__ fc_b,
                            const float* __restrict__ fco_w, const float* __restrict__ fco_b,
                            const float* __restrict__ fca_w, const float* __restrict__ fca_b,
                            float* __restrict__ out) {
    int bs = blockIdx.x;          // b*S + s
    int b  = bs / SS;
    int s  = bs % SS;
    int j  = threadIdx.x;
    const float* prow = pooled + (long)(s * BB + b) * HID;
    float acc = fc_b[j];
    #pragma unroll 4
    for (int k = 0; k < HID; ++k) acc += fc_w[j * HID + k] * prow[k];
    float f = fmaxf(acc, 0.f);
    __shared__ float ro[128], ra[128];
    ro[j] = f * fco_w[j];
    ra[j] = f * fca_w[j];
    __syncthreads();
    for (int off = 64; off; off >>= 1) {
        if (j < off) { ro[j] += ro[j + off]; ra[j] += ra[j + off]; }
        __syncthreads();
    }
    if (j == 0) {
        out[bs]           = ro[0] + fco_b[0];
        out[BB * SS + bs] = ra[0] + fca_b[0];
    }
}

// ---------------------------------------------------------------------------
extern "C" void kernel_launch(void* const* d_in, const int* in_sizes, int n_in,
                              void* d_out, int out_size, void* d_ws, size_t ws_size,
                              hipStream_t stream) {
    const float* x      = (const float*)d_in[0];
    const float* conv_w = (const float*)d_in[1];
    const float* conv_b = (const float*)d_in[2];
    const float* init_h = (const float*)d_in[3];
    const float* init_c = (const float*)d_in[4];
    const float* fc_w   = (const float*)d_in[5];
    const float* fc_b   = (const float*)d_in[6];
    const float* fco_w  = (const float*)d_in[7];
    const float* fco_b  = (const float*)d_in[8];
    const float* fca_w  = (const float*)d_in[9];
    const float* fca_b  = (const float*)d_in[10];
    float* out = (float*)d_out;

    // Workspace carve-up — total ~60 MB.
    unsigned short* wh  = (unsigned short*)d_ws;            // 2,359,296
    unsigned short* xph = wh  + (long)DEPTH * COUT * KFULL; // SS*ACT = 8,388,608
    unsigned short* s1h = xph + (long)SS * ACT;
    unsigned short* s2h = s1h + (long)SS * ACT;
    unsigned short* h1h = s2h + (long)SS * ACT;             // ACT each
    unsigned short* h2h = h1h + ACT;
    float* c1     = (float*)(h2h + ACT);                    // ACT f32
    float* c2     = c1 + ACT;
    float* pooled = c2 + ACT;                               // 16,384
    unsigned short* zp = (unsigned short*)(pooled + SS * BB * HID); // 256 B zeros

    transpose_w_kernel<<<(DEPTH * K9 * COUT + 255) / 256, 256, 0, stream>>>(conv_w, wh);
    pack_x_kernel<<<dim3(SS * BB, HW / 64), 256, 0, stream>>>(x, (unsigned*)xph);
    init_state_kernel<<<ACT / 256, 256, 0, stream>>>(init_h, init_c, h1h, c1, 0);
    init_state_kernel<<<ACT / 256, 256, 0, stream>>>(init_h, init_c, h2h, c2, 1);
    zero_kernel<<<1, 64, 0, stream>>>((unsigned*)zp);

    for (int t = 0; t <= SS; ++t) {
        int do1 = (t < SS) ? 1 : 0;
        int do2 = (t >= 1) ? 1 : 0;
        int t1 = (t < SS) ? t : SS - 1;          // clamped for safe ptr arith
        int u2 = (t >= 1) ? t - 1 : 0;
        const unsigned short* ax1h = xph + (long)t1 * ACT;
        const unsigned short* ah1h = (t1 == 0) ? h1h : s1h + (long)(t1 - 1) * ACT;
        unsigned short* ao1h = s1h + (long)t1 * ACT;
        const unsigned short* ax2h = s1h + (long)u2 * ACT;
        const unsigned short* ah2h = (u2 == 0) ? h2h : s2h + (long)(u2 - 1) * ACT;
        unsigned short* ao2h = s2h + (long)u2 * ACT;
        step_dual<<<512, 256, 0, stream>>>(
            ax1h, ah1h, c1, ao1h,
            ax2h, ah2h, c2, ao2h,
            wh, conv_b, zp, do1, do2);
    }

    pool_kernel<<<SS * BB, 128, 0, stream>>>(s2h, pooled);
    head_kernel<<<BB * SS, 128, 0, stream>>>(pooled, fc_w, fc_b, fco_w, fco_b, fca_w, fca_b, out);
}